// Round 12
// baseline (842.173 us; speedup 1.0000x reference)
//
#include <hip/hip_runtime.h>
#include <hip/hip_bf16.h>

// ---------------- constants ----------------
// C=192, H=W=T=32, WS=4, SS=2, NH=6, HD=32, N=64 tokens/window
// L = 32768 tokens/batch, B=2 -> M = 65536 rows everywhere.
#define DI __device__ __forceinline__

typedef short bf16x8 __attribute__((ext_vector_type(8)));
typedef float f32x4 __attribute__((ext_vector_type(4)));
typedef short s16x4 __attribute__((ext_vector_type(4)));

DI short f2bf(float f) {
    __hip_bfloat16 h = __float2bfloat16(f);
    return *reinterpret_cast<short*>(&h);
}

DI void gload_lds16(const short* gsrc, short* ldst) {
    __builtin_amdgcn_global_load_lds(
        (const __attribute__((address_space(1))) void*)gsrc,
        (__attribute__((address_space(3))) void*)ldst, 16, 0, 0);
}

// region label along one axis for the shift mask: [0,28)->0, [28,30)->1, [30,32)->2
DI int reg3(int p) { return p < 28 ? 0 : (p < 30 ? 1 : 2); }

// ---------------- input transpose: x (B,C,L) -> xf (B,L,C) f32 ----------------
__global__ __launch_bounds__(256) void transpose_in(const float* __restrict__ x,
                                                    float* __restrict__ xf) {
    __shared__ float tile[32][33];
    int b = blockIdx.z;
    int c0 = blockIdx.y * 32;
    int l0 = blockIdx.x * 32;
    int tx = threadIdx.x, ty = threadIdx.y;  // 32 x 8
#pragma unroll
    for (int i = 0; i < 32; i += 8)
        tile[ty + i][tx] = x[(long)(b * 192 + c0 + ty + i) * 32768 + l0 + tx];
    __syncthreads();
#pragma unroll
    for (int i = 0; i < 32; i += 8)
        xf[(long)(b * 32768 + l0 + ty + i) * 192 + c0 + tx] = tile[tx][ty + i];
}

// ---------------- weight prep ----------------
__global__ __launch_bounds__(256) void prep_w(const float* __restrict__ qkv_w,
                                              const float* __restrict__ proj_w,
                                              const float* __restrict__ fc1_w,
                                              const float* __restrict__ fc2_w,
                                              const float* __restrict__ pw_w,
                                              short* __restrict__ wt) {
    int i = blockIdx.x * 256 + threadIdx.x;
    float v;
    if (i < 1769472) {
        int b4 = i / 442368, r = i - b4 * 442368;
        if (r < 110592) { int n = r / 192, k = r - n * 192; v = qkv_w[b4 * 110592 + k * 576 + n]; }
        else if (r < 147456) { int r2 = r - 110592; int n = r2 / 192, k = r2 - n * 192; v = proj_w[b4 * 36864 + k * 192 + n]; }
        else if (r < 294912) { int r2 = r - 147456; int n = r2 / 192, k = r2 - n * 192; v = fc1_w[b4 * 147456 + k * 768 + n]; }
        else { int r2 = r - 294912; int n = r2 / 768, k = r2 - n * 768; v = fc2_w[b4 * 147456 + k * 192 + n]; }
        wt[i] = f2bf(v);
    } else {
        int r = i - 1769472;
        wt[i] = f2bf(pw_w[r]);
    }
}

// ---------------- fused LN1 + QKV: out = LN(gather(x)) @ Wqkv + b ----------------
__global__ __launch_bounds__(256) void qkv_k(const float* __restrict__ XF,
                                             const short* __restrict__ Wg,  // qkvT (576,192)
                                             const float* __restrict__ bias,
                                             const float* __restrict__ n1g,
                                             const float* __restrict__ n1b,
                                             short* __restrict__ out, int shift) {
    __shared__ short Ws[2][12288];
    const int tid = threadIdx.x;
    const int wv = tid >> 6, lane = tid & 63;
    const int lr = lane & 15, lg = lane >> 4;
    const int mt = ((blockIdx.x & 7) << 6) + (blockIdx.x >> 3);  // XCD swizzle, 512 blocks
    const int m0 = mt << 7;

    // ---- LN1 prologue with roll+window-partition gather ----
    bf16x8 areg[2][6];
#pragma unroll
    for (int mf = 0; mf < 2; mf++) {
        int row = m0 + (wv << 5) + (mf << 4) + lr;
        int b = row >> 15, r = row & 32767, widx = r >> 6, n = r & 63;
        int wh = widx >> 6, ww = (widx >> 3) & 7, wt = widx & 7;
        int ih = n >> 4, iw = (n >> 2) & 3, it = n & 3;
        int h = ((wh << 2) + ih + shift) & 31;
        int w = ((ww << 2) + iw + shift) & 31;
        int t = ((wt << 2) + it + shift) & 31;
        const float* rp = XF + ((long)(b << 15) + (h << 10) + (w << 5) + t) * 192;
        f32x4 xv[6][2];
        float s = 0.f, sq = 0.f;
#pragma unroll
        for (int kk = 0; kk < 6; kk++)
#pragma unroll
            for (int q = 0; q < 2; q++) {
                xv[kk][q] = *(const f32x4*)(rp + kk * 32 + (lg << 3) + q * 4);
#pragma unroll
                for (int e = 0; e < 4; e++) {
                    s += xv[kk][q][e];
                    sq += xv[kk][q][e] * xv[kk][q][e];
                }
            }
        s += __shfl_xor(s, 16, 64); s += __shfl_xor(s, 32, 64);
        sq += __shfl_xor(sq, 16, 64); sq += __shfl_xor(sq, 32, 64);
        float mu = s * (1.f / 192.f);
        float var = sq * (1.f / 192.f) - mu * mu;
        float rstd = rsqrtf(var + 1e-5f);
#pragma unroll
        for (int kk = 0; kk < 6; kk++) {
            int cb = kk * 32 + (lg << 3);
            f32x4 g0 = *(const f32x4*)(n1g + cb), g1 = *(const f32x4*)(n1g + cb + 4);
            f32x4 b0 = *(const f32x4*)(n1b + cb), b1v = *(const f32x4*)(n1b + cb + 4);
            bf16x8 tt;
#pragma unroll
            for (int e = 0; e < 4; e++) {
                tt[e] = f2bf((xv[kk][0][e] - mu) * rstd * g0[e] + b0[e]);
                tt[e + 4] = f2bf((xv[kk][1][e] - mu) * rstd * g1[e] + b1v[e]);
            }
            areg[mf][kk] = tt;
        }
    }

    auto stage = [&](int jc, int buf) {
#pragma unroll
        for (int q = 0; q < 6; q++) {
            int base = (wv * 6 + q) * 512;
            int E = base + lane * 8;
            int row = E / 192;
            int cb = (E - row * 192) >> 3;
            gload_lds16(Wg + (long)(jc * 64 + row) * 192 + ((cb ^ (row & 7)) << 3),
                        &Ws[buf][base]);
        }
    };

    stage(0, 0);
    __syncthreads();

    for (int j = 0; j < 9; j++) {
        if (j < 8) stage(j + 1, (j + 1) & 1);
        const short* W = Ws[j & 1];
        f32x4 acc[2][4] = {};
#pragma unroll
        for (int kk = 0; kk < 6; kk++) {
            int cb = (kk << 2) + lg;
            bf16x8 wf[4];
#pragma unroll
            for (int nf = 0; nf < 4; nf++) {
                int r = (nf << 4) + lr;
                wf[nf] = *(const bf16x8*)(W + r * 192 + ((cb ^ (r & 7)) << 3));
            }
#pragma unroll
            for (int mf = 0; mf < 2; mf++)
#pragma unroll
                for (int nf = 0; nf < 4; nf++)
                    acc[mf][nf] = __builtin_amdgcn_mfma_f32_16x16x32_bf16(
                        areg[mf][kk], wf[nf], acc[mf][nf], 0, 0, 0);
        }
#pragma unroll
        for (int mf = 0; mf < 2; mf++) {
#pragma unroll
            for (int nf = 0; nf < 4; nf++) {
                int col = j * 64 + (nf << 4) + lr;
                float bv = bias[col];
#pragma unroll
                for (int e = 0; e < 4; e++) {
                    int row = m0 + (wv << 5) + (mf << 4) + (lg << 2) + e;
                    out[(long)row * 576 + col] = f2bf(acc[mf][nf][e] + bv);
                }
            }
        }
        __syncthreads();
    }
}

// ---------------- A-in-regs GEMM with full W in LDS (K=192, N=192) ----------------
// MODE 3: proj -> window-reverse+roll, resid += v
// MODE 4: pointwise conv -> BN + ReLU, f32 channel-major out
template <int MODE>
__global__ __launch_bounds__(256) void wk_k(const short* __restrict__ A,
                                            const short* __restrict__ Wg,  // (192,192)
                                            const float* __restrict__ bias,
                                            float* __restrict__ resid, float* __restrict__ outF,
                                            const float* __restrict__ bng,
                                            const float* __restrict__ bnb, int shift) {
    __shared__ short Ws[36864];
    const int tid = threadIdx.x;
    const int wv = tid >> 6, lane = tid & 63;
    const int lr = lane & 15, lg = lane >> 4;
    const int mt = ((blockIdx.x & 7) << 6) + (blockIdx.x >> 3);  // 512 blocks
    const int m0 = mt << 7;

    bf16x8 areg[2][6];
#pragma unroll
    for (int mf = 0; mf < 2; mf++)
#pragma unroll
        for (int kk = 0; kk < 6; kk++)
            areg[mf][kk] = *(const bf16x8*)(A + (long)(m0 + (wv << 5) + (mf << 4) + lr) * 192 + kk * 32 + (lg << 3));

#pragma unroll
    for (int q = 0; q < 18; q++) {
        int base = (wv * 18 + q) * 512;
        int E = base + lane * 8;
        int row = E / 192;
        int cb = (E - row * 192) >> 3;
        gload_lds16(Wg + (long)row * 192 + ((cb ^ (row & 7)) << 3), Ws + base);
    }
    __syncthreads();

    f32x4 acc[2][12] = {};
#pragma unroll
    for (int kk = 0; kk < 6; kk++) {
        int cb = (kk << 2) + lg;
#pragma unroll
        for (int njb = 0; njb < 3; njb++) {
            bf16x8 wf[4];
#pragma unroll
            for (int q = 0; q < 4; q++) {
                int r = ((njb * 4 + q) << 4) + lr;
                wf[q] = *(const bf16x8*)(Ws + r * 192 + ((cb ^ (r & 7)) << 3));
            }
#pragma unroll
            for (int mf = 0; mf < 2; mf++)
#pragma unroll
                for (int q = 0; q < 4; q++)
                    acc[mf][njb * 4 + q] = __builtin_amdgcn_mfma_f32_16x16x32_bf16(
                        areg[mf][kk], wf[q], acc[mf][njb * 4 + q], 0, 0, 0);
        }
    }

#pragma unroll
    for (int mf = 0; mf < 2; mf++) {
        int rbase = m0 + (wv << 5) + (mf << 4) + (lg << 2);
#pragma unroll
        for (int nj = 0; nj < 12; nj++) {
            int col = (nj << 4) + lr;
            float bv = bias[col];
            if (MODE == 4) {
                float sc = 0.9999950000374997f * bng[col];
                float bb = bnb[col];
                f32x4 o;
#pragma unroll
                for (int e = 0; e < 4; e++) {
                    float v = (acc[mf][nj][e] + bv) * sc + bb;
                    o[e] = v > 0.f ? v : 0.f;
                }
                int b = rbase >> 15, l = rbase & 32767;
                *(f32x4*)(outF + ((long)(b * 192 + col) << 15) + l) = o;
            } else {  // MODE 3
#pragma unroll
                for (int e = 0; e < 4; e++) {
                    int r = rbase + e;
                    int b = r >> 15, rr = r & 32767, widx = rr >> 6, n = rr & 63;
                    int wh = widx >> 6, ww = (widx >> 3) & 7, wt = widx & 7;
                    int ih = n >> 4, iw = (n >> 2) & 3, it = n & 3;
                    int h = ((wh << 2) + ih + shift) & 31;
                    int w = ((ww << 2) + iw + shift) & 31;
                    int t = ((wt << 2) + it + shift) & 31;
                    long tok = (long)(b << 15) + (h << 10) + (w << 5) + t;
                    resid[tok * 192 + col] += acc[mf][nj][e] + bv;
                }
            }
        }
    }
}

// ---------------- fused LN2+MLP v7b: 8 waves x 16 rows, 2 blocks/CU ----------------
// launch_bounds(512,2): empirical hipcc rule caps arch-VGPR at 256/arg2; (512,4)
// and 1024-thread blocks force 64 -> spills (rounds 9-11). W2 XOR includes
// (r>>2)&3 (32-short rows wrap banks every 2 rows). Hs stride 56 shorts: 16B
// aligned b128 rows + 8-bank spread (2-way, free).
// LDS = 48KB W dbuf + 14KB Hs = 63.5KB -> 2 blocks/CU.
__global__ __launch_bounds__(512, 2) void mlp_k(const float* __restrict__ XF,
                                                const short* __restrict__ W1g,  // fc1T (768,192)
                                                const short* __restrict__ W2g,  // fc2T (192,768)
                                                const float* __restrict__ b1,
                                                const float* __restrict__ b2,
                                                const float* __restrict__ n2g,
                                                const float* __restrict__ n2b,
                                                float* __restrict__ resid) {
    __shared__ short Wbuf[2][12288];  // per buf: W1 32x192 @0, W2 192x32 @6144
    __shared__ short Hs[8][896];      // per wave: 16 rows x stride 56
    const int tid = threadIdx.x;
    const int wv = tid >> 6, lane = tid & 63;
    const int lr = lane & 15, lg = lane >> 4;
    const int mt = ((blockIdx.x & 7) << 6) + (blockIdx.x >> 3);  // XCD swizzle, 512 blocks
    const int m0 = mt << 7;
    short* hw = &Hs[wv][0];

    // ---- LN2 prologue: 16 rows/wave -> normalized bf16 fragments in registers ----
    bf16x8 areg[6];
    {
        const float* rp = XF + (long)(m0 + (wv << 4) + lr) * 192;
        f32x4 xv[6][2];
        float s = 0.f, sq = 0.f;
#pragma unroll
        for (int kk = 0; kk < 6; kk++)
#pragma unroll
            for (int q = 0; q < 2; q++) {
                xv[kk][q] = *(const f32x4*)(rp + kk * 32 + (lg << 3) + q * 4);
#pragma unroll
                for (int e = 0; e < 4; e++) {
                    s += xv[kk][q][e];
                    sq += xv[kk][q][e] * xv[kk][q][e];
                }
            }
        s += __shfl_xor(s, 16, 64); s += __shfl_xor(s, 32, 64);
        sq += __shfl_xor(sq, 16, 64); sq += __shfl_xor(sq, 32, 64);
        float mu = s * (1.f / 192.f);
        float var = sq * (1.f / 192.f) - mu * mu;
        float rstd = rsqrtf(var + 1e-5f);
#pragma unroll
        for (int kk = 0; kk < 6; kk++) {
            int cb = kk * 32 + (lg << 3);
            f32x4 g0 = *(const f32x4*)(n2g + cb), g1 = *(const f32x4*)(n2g + cb + 4);
            f32x4 b0 = *(const f32x4*)(n2b + cb), b1v = *(const f32x4*)(n2b + cb + 4);
            bf16x8 t;
#pragma unroll
            for (int e = 0; e < 4; e++) {
                t[e] = f2bf((xv[kk][0][e] - mu) * rstd * g0[e] + b0[e]);
                t[e + 4] = f2bf((xv[kk][1][e] - mu) * rstd * g1[e] + b1v[e]);
            }
            areg[kk] = t;
        }
    }

    // ---- async W chunk staging: 24 gloads = 8 waves x 3 ----
    auto stage = [&](int jc, int buf) {
#pragma unroll
        for (int q = 0; q < 3; q++) {
            int g = wv * 3 + q;  // 0..23
            if (g < 12) {        // W1 chunk: 32x192, 8-row XOR (stride 192 -> bank-neutral)
                int base = g * 512;
                int E = base + lane * 8;
                int row = E / 192;
                int cb = (E - row * 192) >> 3;
                gload_lds16(W1g + (long)(jc * 32 + row) * 192 + ((cb ^ (row & 7)) << 3),
                            &Wbuf[buf][base]);
            } else {             // W2 chunk: 192x32, XOR mixes (row&3)^((row>>2)&3)
                int base = (g - 12) * 512;
                int E = base + lane * 8;
                int row = E >> 5;
                int cb = (E & 31) >> 3;
                int sw = (row & 3) ^ ((row >> 2) & 3);
                gload_lds16(W2g + (long)row * 768 + jc * 32 + ((cb ^ sw) << 3),
                            &Wbuf[buf][6144 + base]);
            }
        }
    };

    stage(0, 0);
    __syncthreads();  // chunk 0 staged

    f32x4 acc[12] = {};

    for (int j = 0; j < 24; j++) {
        if (j < 23) stage(j + 1, (j + 1) & 1);  // async prefetch under this chunk
        const short* W1s = Wbuf[j & 1];
        const short* W2s = Wbuf[j & 1] + 6144;

        // ---- GEMM1 (swapped): hacc[hf] = W1frag x areg ----
        f32x4 hacc[2] = {};
#pragma unroll
        for (int kk = 0; kk < 6; kk++) {
            int cb = (kk << 2) + lg;
            bf16x8 wf[2];
#pragma unroll
            for (int hf = 0; hf < 2; hf++) {
                int r = (hf << 4) + lr;
                wf[hf] = *(const bf16x8*)(W1s + r * 192 + ((cb ^ (r & 7)) << 3));
            }
#pragma unroll
            for (int hf = 0; hf < 2; hf++)
                hacc[hf] = __builtin_amdgcn_mfma_f32_16x16x32_bf16(
                    wf[hf], areg[kk], hacc[hf], 0, 0, 0);
        }

        // ---- GELU(+b1), packed b64 writes to wave-private h [16][56] ----
#pragma unroll
        for (int hf = 0; hf < 2; hf++) {
            f32x4 bv = *(const f32x4*)(b1 + j * 32 + (hf << 4) + (lg << 2));
            s16x4 hv;
#pragma unroll
            for (int e = 0; e < 4; e++) {
                float v = hacc[hf][e] + bv[e];
                float inner = fmaf(-0.07135481627f, v * v, -1.595769122f);
                float eterm = __expf(v * inner);  // exp(-2u)
                float gl = v * __builtin_amdgcn_rcpf(1.f + eterm);
                hv[e] = f2bf(gl);
            }
            *(s16x4*)(hw + lr * 56 + (hf << 4) + (lg << 2)) = hv;
        }
        // wave-local h exchange: LDS queue drain only, no block barrier
        asm volatile("s_waitcnt lgkmcnt(0)" ::: "memory");

        // ---- GEMM2: acc += h @ W2 (K=32 -> single kk) ----
        {
            bf16x8 ah = *(const bf16x8*)(hw + lr * 56 + (lg << 3));
            bf16x8 bw[12];
#pragma unroll
            for (int nj = 0; nj < 12; nj++) {
                int r = (nj << 4) + lr;
                int sw = (r & 3) ^ ((r >> 2) & 3);
                bw[nj] = *(const bf16x8*)(W2s + r * 32 + ((lg ^ sw) << 3));
            }
#pragma unroll
            for (int nj = 0; nj < 12; nj++)
                acc[nj] = __builtin_amdgcn_mfma_f32_16x16x32_bf16(
                    ah, bw[nj], acc[nj], 0, 0, 0);
        }
        // single barrier: all waves done with Wbuf[j&1]; vmcnt drained -> next buf staged
        __syncthreads();
    }

    // ---- epilogue: resid += acc + b2 ----
    {
        int rbase = m0 + (wv << 4) + (lg << 2);
#pragma unroll
        for (int nj = 0; nj < 12; nj++) {
            int col = (nj << 4) + lr;
            float bv = b2[col];
#pragma unroll
            for (int e = 0; e < 4; e++) {
                long r = rbase + e;
                resid[r * 192 + col] += acc[nj][e] + bv;
            }
        }
    }
}

// ---------------- windowed attention: one wave per (window, head) ----------------
__global__ __launch_bounds__(256) void attn_k(const short* __restrict__ qkv,
                                              const float* __restrict__ rpb,  // (343,6)
                                              short* __restrict__ o, int shifted) {
    __shared__ short lds[4 * 6144];
    const int wv = threadIdx.x >> 6, lane = threadIdx.x & 63;
    short* vT = lds + wv * 6144;
    short* P = lds + wv * 6144 + 2048;
    const int task = blockIdx.x * 4 + wv;
    const int win = task / 6, head = task - win * 6;
    const int lr = lane & 15, lg = lane >> 4;
    const long qbase = (long)win * 64 * 576 + head * 32;

    bf16x8 aq[4], bk[4];
#pragma unroll
    for (int bi = 0; bi < 4; bi++)
        aq[bi] = *(const bf16x8*)(qkv + qbase + (long)((bi << 4) + lr) * 576 + (lg << 3));
#pragma unroll
    for (int bj = 0; bj < 4; bj++)
        bk[bj] = *(const bf16x8*)(qkv + qbase + 192 + (long)((bj << 4) + lr) * 576 + (lg << 3));
    f32x4 s[4][4] = {};
#pragma unroll
    for (int bi = 0; bi < 4; bi++)
#pragma unroll
        for (int bj = 0; bj < 4; bj++)
            s[bi][bj] = __builtin_amdgcn_mfma_f32_16x16x32_bf16(aq[bi], bk[bj], s[bi][bj], 0, 0, 0);

#pragma unroll
    for (int j = 0; j < 4; j++) {
        bf16x8 vv = *(const bf16x8*)(qkv + qbase + 384 + (long)lane * 576 + (j << 3));
#pragma unroll
        for (int e = 0; e < 8; e++) {
            int d = (j << 3) + e;
            vT[d * 64 + (((lane >> 3) ^ (d & 7)) << 3) + (lane & 7)] = vv[e];
        }
    }

    const float SCALE = 0.17677669529663687f;
    int widx = win & 511;
    int wh = widx >> 6, ww = (widx >> 3) & 7, wt = widx & 7;
    int ihm[4], iwm[4], itm[4], lblm[4];
#pragma unroll
    for (int bj = 0; bj < 4; bj++) {
        int m = (bj << 4) + lr;
        ihm[bj] = m >> 4; iwm[bj] = (m >> 2) & 3; itm[bj] = m & 3;
        lblm[bj] = reg3((wh << 2) + ihm[bj]) * 9 + reg3((ww << 2) + iwm[bj]) * 3 + reg3((wt << 2) + itm[bj]);
    }
#pragma unroll
    for (int bi = 0; bi < 4; bi++) {
#pragma unroll
        for (int e = 0; e < 4; e++) {
            int n = (bi << 4) + (lg << 2) + e;
            int ihn = n >> 4, iwn = (n >> 2) & 3, itn = n & 3;
            int lbln = reg3((wh << 2) + ihn) * 9 + reg3((ww << 2) + iwn) * 3 + reg3((wt << 2) + itn);
#pragma unroll
            for (int bj = 0; bj < 4; bj++) {
                int idx = (ihn - ihm[bj] + 3) * 49 + (iwn - iwm[bj] + 3) * 7 + (itn - itm[bj] + 3);
                float bias = rpb[idx * 6 + head];
                float val = s[bi][bj][e] * SCALE + bias;
                if (shifted && lbln != lblm[bj]) val -= 100.f;
                s[bi][bj][e] = val;
            }
        }
    }

#pragma unroll
    for (int bi = 0; bi < 4; bi++) {
#pragma unroll
        for (int e = 0; e < 4; e++) {
            float mx = s[bi][0][e];
#pragma unroll
            for (int bj = 1; bj < 4; bj++) mx = fmaxf(mx, s[bi][bj][e]);
#pragma unroll
            for (int off = 1; off < 16; off <<= 1) mx = fmaxf(mx, __shfl_xor(mx, off, 64));
            float sm = 0.f;
#pragma unroll
            for (int bj = 0; bj < 4; bj++) {
                float p = __expf(s[bi][bj][e] - mx);
                s[bi][bj][e] = p;
                sm += p;
            }
#pragma unroll
            for (int off = 1; off < 16; off <<= 1) sm += __shfl_xor(sm, off, 64);
            float rinv = 1.f / sm;
            int n = (bi << 4) + (lg << 2) + e;
#pragma unroll
            for (int bj = 0; bj < 4; bj++) {
                int m = (bj << 4) + lr;
                P[n * 64 + (((m >> 3) ^ (n & 7)) << 3) + (m & 7)] = f2bf(s[bi][bj][e] * rinv);
            }
        }
    }

    f32x4 oacc[4][2] = {};
#pragma unroll
    for (int ks = 0; ks < 2; ks++) {
        bf16x8 ap[4], bv2[2];
        int kb = (ks << 2) + lg;
#pragma unroll
        for (int bi = 0; bi < 4; bi++) {
            int r = (bi << 4) + lr;
            ap[bi] = *(const bf16x8*)(P + r * 64 + ((kb ^ (r & 7)) << 3));
        }
#pragma unroll
        for (int nf = 0; nf < 2; nf++) {
            int d = (nf << 4) + lr;
            bv2[nf] = *(const bf16x8*)(vT + d * 64 + ((kb ^ (d & 7)) << 3));
        }
#pragma unroll
        for (int bi = 0; bi < 4; bi++)
#pragma unroll
            for (int nf = 0; nf < 2; nf++)
                oacc[bi][nf] = __builtin_amdgcn_mfma_f32_16x16x32_bf16(ap[bi], bv2[nf], oacc[bi][nf], 0, 0, 0);
    }
#pragma unroll
    for (int bi = 0; bi < 4; bi++)
#pragma unroll
        for (int nf = 0; nf < 2; nf++)
#pragma unroll
            for (int e = 0; e < 4; e++) {
                int n = (bi << 4) + (lg << 2) + e;
                int d = (nf << 4) + lr;
                o[((long)win * 64 + n) * 192 + head * 32 + d] = f2bf(oacc[bi][nf][e]);
            }
}

// ---------------- depthwise 3x3x3 conv, register-blocked along t ----------------
__global__ __launch_bounds__(192) void dw_k(const float* __restrict__ xf,
                                            const float* __restrict__ w,
                                            const float* __restrict__ db,
                                            short* __restrict__ out) {
    int c = threadIdx.x;
    int blk = blockIdx.x;
    int t0 = (blk & 3) << 3;
    int bhw = blk >> 2;
    int b = bhw >> 10, h = (bhw >> 5) & 31, wq = bhw & 31;

    float wr[27];
#pragma unroll
    for (int k = 0; k < 27; k++) wr[k] = w[c * 27 + k];
    float bias = db[c];
    float acc[8];
#pragma unroll
    for (int j = 0; j < 8; j++) acc[j] = bias;

#pragma unroll
    for (int a = 0; a < 3; a++) {
        int hh = h + a - 1;
        if (hh < 0 || hh > 31) continue;
#pragma unroll
        for (int bb = 0; bb < 3; bb++) {
            int ww = wq + bb - 1;
            if (ww < 0 || ww > 31) continue;
            const float* base = xf + ((long)(b << 15) + (hh << 10) + (ww << 5)) * 192 + c;
            float val[10];
#pragma unroll
            for (int tt = 0; tt < 10; tt++) {
                int t = t0 + tt - 1;
                val[tt] = (t >= 0 && t < 32) ? base[t * 192] : 0.f;
            }
#pragma unroll
            for (int d = 0; d < 3; d++) {
                float wv = wr[a * 9 + bb * 3 + d];
#pragma unroll
                for (int j = 0; j < 8; j++)
                    acc[j] = fmaf(val[j + d], wv, acc[j]);
            }
        }
    }
    long obase = ((long)(b << 15) + (h << 10) + (wq << 5) + t0) * 192 + c;
#pragma unroll
    for (int j = 0; j < 8; j++) out[obase + j * 192] = f2bf(acc[j]);
}

// ---------------- launch ----------------
extern "C" void kernel_launch(void* const* d_in, const int* in_sizes, int n_in,
                              void* d_out, int out_size, void* d_ws, size_t ws_size,
                              hipStream_t stream) {
    const float* x      = (const float*)d_in[0];
    const float* n1g    = (const float*)d_in[1];
    const float* n1b    = (const float*)d_in[2];
    const float* qkv_w  = (const float*)d_in[3];
    const float* qkv_b  = (const float*)d_in[4];
    const float* rpb    = (const float*)d_in[5];
    const float* proj_w = (const float*)d_in[6];
    const float* proj_b = (const float*)d_in[7];
    const float* n2g    = (const float*)d_in[8];
    const float* n2b    = (const float*)d_in[9];
    const float* fc1_w  = (const float*)d_in[10];
    const float* fc1_b  = (const float*)d_in[11];
    const float* fc2_w  = (const float*)d_in[12];
    const float* fc2_b  = (const float*)d_in[13];
    const float* dw_w   = (const float*)d_in[14];
    const float* dw_b   = (const float*)d_in[15];
    const float* pw_w   = (const float*)d_in[16];
    const float* pw_b   = (const float*)d_in[17];
    const float* bn_g   = (const float*)d_in[18];
    const float* bn_b   = (const float*)d_in[19];
    float* outF = (float*)d_out;

    char* ws = (char*)d_ws;
    float* XF = (float*)ws;
    short* Abuf = (short*)(ws + 50331648);
    short* Bbuf = (short*)(ws + 150994944);
    short* WT = (short*)(ws + 226492416);

    transpose_in<<<dim3(1024, 6, 2), dim3(32, 8), 0, stream>>>(x, XF);
    prep_w<<<7056, 256, 0, stream>>>(qkv_w, proj_w, fc1_w, fc2_w, pw_w, WT);

    for (int i = 0; i < 4; i++) {
        int shifted = i & 1;
        int shift = shifted ? 2 : 0;
        qkv_k<<<512, 256, 0, stream>>>(XF, WT + (long)i * 442368, qkv_b + i * 576,
                                       n1g + i * 192, n1b + i * 192, Bbuf, shift);
        attn_k<<<1536, 256, 0, stream>>>(Bbuf, rpb + i * 2058, Abuf, shifted);
        wk_k<3><<<512, 256, 0, stream>>>(Abuf, WT + (long)i * 442368 + 110592, proj_b + i * 192,
                                         XF, nullptr, nullptr, nullptr, shift);
        mlp_k<<<512, 512, 0, stream>>>(XF, WT + (long)i * 442368 + 147456,
                                       WT + (long)i * 442368 + 294912,
                                       fc1_b + i * 768, fc2_b + i * 192,
                                       n2g + i * 192, n2b + i * 192, XF);
    }

    dw_k<<<8192, 192, 0, stream>>>(XF, dw_w, dw_b, Abuf);
    wk_k<4><<<512, 256, 0, stream>>>(Abuf, WT + 1769472, pw_b,
                                     nullptr, outF, bn_g, bn_b, 0);
}

// Round 13
// 794.015 us; speedup vs baseline: 1.0607x; 1.0607x over previous
//
#include <hip/hip_runtime.h>
#include <hip/hip_bf16.h>

// ---------------- constants ----------------
// C=192, H=W=T=32, WS=4, SS=2, NH=6, HD=32, N=64 tokens/window
// L = 32768 tokens/batch, B=2 -> M = 65536 rows everywhere.
#define DI __device__ __forceinline__

typedef short bf16x8 __attribute__((ext_vector_type(8)));
typedef float f32x4 __attribute__((ext_vector_type(4)));
typedef short s16x4 __attribute__((ext_vector_type(4)));

DI short f2bf(float f) {
    __hip_bfloat16 h = __float2bfloat16(f);
    return *reinterpret_cast<short*>(&h);
}

DI void gload_lds16(const short* gsrc, short* ldst) {
    __builtin_amdgcn_global_load_lds(
        (const __attribute__((address_space(1))) void*)gsrc,
        (__attribute__((address_space(3))) void*)ldst, 16, 0, 0);
}

// region label along one axis for the shift mask: [0,28)->0, [28,30)->1, [30,32)->2
DI int reg3(int p) { return p < 28 ? 0 : (p < 30 ? 1 : 2); }

// ---------------- input transpose: x (B,C,L) -> xf (B,L,C) f32 ----------------
__global__ __launch_bounds__(256) void transpose_in(const float* __restrict__ x,
                                                    float* __restrict__ xf) {
    __shared__ float tile[32][33];
    int b = blockIdx.z;
    int c0 = blockIdx.y * 32;
    int l0 = blockIdx.x * 32;
    int tx = threadIdx.x, ty = threadIdx.y;  // 32 x 8
#pragma unroll
    for (int i = 0; i < 32; i += 8)
        tile[ty + i][tx] = x[(long)(b * 192 + c0 + ty + i) * 32768 + l0 + tx];
    __syncthreads();
#pragma unroll
    for (int i = 0; i < 32; i += 8)
        xf[(long)(b * 32768 + l0 + ty + i) * 192 + c0 + tx] = tile[tx][ty + i];
}

// ---------------- weight prep ----------------
__global__ __launch_bounds__(256) void prep_w(const float* __restrict__ qkv_w,
                                              const float* __restrict__ proj_w,
                                              const float* __restrict__ fc1_w,
                                              const float* __restrict__ fc2_w,
                                              const float* __restrict__ pw_w,
                                              short* __restrict__ wt) {
    int i = blockIdx.x * 256 + threadIdx.x;
    float v;
    if (i < 1769472) {
        int b4 = i / 442368, r = i - b4 * 442368;
        if (r < 110592) { int n = r / 192, k = r - n * 192; v = qkv_w[b4 * 110592 + k * 576 + n]; }
        else if (r < 147456) { int r2 = r - 110592; int n = r2 / 192, k = r2 - n * 192; v = proj_w[b4 * 36864 + k * 192 + n]; }
        else if (r < 294912) { int r2 = r - 147456; int n = r2 / 192, k = r2 - n * 192; v = fc1_w[b4 * 147456 + k * 768 + n]; }
        else { int r2 = r - 294912; int n = r2 / 768, k = r2 - n * 768; v = fc2_w[b4 * 147456 + k * 192 + n]; }
        wt[i] = f2bf(v);
    } else {
        int r = i - 1769472;
        wt[i] = f2bf(pw_w[r]);
    }
}

// ---------------- fused LN1 + QKV: out = LN(gather(x)) @ Wqkv + b ----------------
// Epilogue: wave-local LDS bounce -> 64-128B-run coalesced global stores.
__global__ __launch_bounds__(256) void qkv_k(const float* __restrict__ XF,
                                             const short* __restrict__ Wg,  // qkvT (576,192)
                                             const float* __restrict__ bias,
                                             const float* __restrict__ n1g,
                                             const float* __restrict__ n1b,
                                             short* __restrict__ out, int shift) {
    __shared__ short Ws[2][12288];
    __shared__ short Qb[4][2048];  // per-wave 32x64 bounce tile
    const int tid = threadIdx.x;
    const int wv = tid >> 6, lane = tid & 63;
    const int lr = lane & 15, lg = lane >> 4;
    const int mt = ((blockIdx.x & 7) << 6) + (blockIdx.x >> 3);  // XCD swizzle, 512 blocks
    const int m0 = mt << 7;
    short* qb = &Qb[wv][0];

    // ---- LN1 prologue with roll+window-partition gather ----
    bf16x8 areg[2][6];
#pragma unroll
    for (int mf = 0; mf < 2; mf++) {
        int row = m0 + (wv << 5) + (mf << 4) + lr;
        int b = row >> 15, r = row & 32767, widx = r >> 6, n = r & 63;
        int wh = widx >> 6, ww = (widx >> 3) & 7, wt = widx & 7;
        int ih = n >> 4, iw = (n >> 2) & 3, it = n & 3;
        int h = ((wh << 2) + ih + shift) & 31;
        int w = ((ww << 2) + iw + shift) & 31;
        int t = ((wt << 2) + it + shift) & 31;
        const float* rp = XF + ((long)(b << 15) + (h << 10) + (w << 5) + t) * 192;
        f32x4 xv[6][2];
        float s = 0.f, sq = 0.f;
#pragma unroll
        for (int kk = 0; kk < 6; kk++)
#pragma unroll
            for (int q = 0; q < 2; q++) {
                xv[kk][q] = *(const f32x4*)(rp + kk * 32 + (lg << 3) + q * 4);
#pragma unroll
                for (int e = 0; e < 4; e++) {
                    s += xv[kk][q][e];
                    sq += xv[kk][q][e] * xv[kk][q][e];
                }
            }
        s += __shfl_xor(s, 16, 64); s += __shfl_xor(s, 32, 64);
        sq += __shfl_xor(sq, 16, 64); sq += __shfl_xor(sq, 32, 64);
        float mu = s * (1.f / 192.f);
        float var = sq * (1.f / 192.f) - mu * mu;
        float rstd = rsqrtf(var + 1e-5f);
#pragma unroll
        for (int kk = 0; kk < 6; kk++) {
            int cb = kk * 32 + (lg << 3);
            f32x4 g0 = *(const f32x4*)(n1g + cb), g1 = *(const f32x4*)(n1g + cb + 4);
            f32x4 b0 = *(const f32x4*)(n1b + cb), b1v = *(const f32x4*)(n1b + cb + 4);
            bf16x8 tt;
#pragma unroll
            for (int e = 0; e < 4; e++) {
                tt[e] = f2bf((xv[kk][0][e] - mu) * rstd * g0[e] + b0[e]);
                tt[e + 4] = f2bf((xv[kk][1][e] - mu) * rstd * g1[e] + b1v[e]);
            }
            areg[mf][kk] = tt;
        }
    }

    auto stage = [&](int jc, int buf) {
#pragma unroll
        for (int q = 0; q < 6; q++) {
            int base = (wv * 6 + q) * 512;
            int E = base + lane * 8;
            int row = E / 192;
            int cb = (E - row * 192) >> 3;
            gload_lds16(Wg + (long)(jc * 64 + row) * 192 + ((cb ^ (row & 7)) << 3),
                        &Ws[buf][base]);
        }
    };

    stage(0, 0);
    __syncthreads();

    for (int j = 0; j < 9; j++) {
        if (j < 8) stage(j + 1, (j + 1) & 1);
        const short* W = Ws[j & 1];
        f32x4 acc[2][4] = {};
#pragma unroll
        for (int kk = 0; kk < 6; kk++) {
            int cb = (kk << 2) + lg;
            bf16x8 wf[4];
#pragma unroll
            for (int nf = 0; nf < 4; nf++) {
                int r = (nf << 4) + lr;
                wf[nf] = *(const bf16x8*)(W + r * 192 + ((cb ^ (r & 7)) << 3));
            }
#pragma unroll
            for (int mf = 0; mf < 2; mf++)
#pragma unroll
                for (int nf = 0; nf < 4; nf++)
                    acc[mf][nf] = __builtin_amdgcn_mfma_f32_16x16x32_bf16(
                        areg[mf][kk], wf[nf], acc[mf][nf], 0, 0, 0);
        }
        // ---- epilogue: wave-private LDS bounce, then 64B-run coalesced stores ----
#pragma unroll
        for (int mf = 0; mf < 2; mf++)
#pragma unroll
            for (int nf = 0; nf < 4; nf++) {
                int col = (nf << 4) + lr;
                float bv = bias[j * 64 + col];
#pragma unroll
                for (int e = 0; e < 4; e++) {
                    int row = (mf << 4) + (lg << 2) + e;
                    int cc = ((((col >> 3) ^ (row & 7)) << 3)) | (col & 7);
                    qb[row * 64 + cc] = f2bf(acc[mf][nf][e] + bv);
                }
            }
        asm volatile("s_waitcnt lgkmcnt(0)" ::: "memory");
        {
            int row = lane >> 2;            // 16 rows per half, 4 lanes/row
            int c0 = (lane & 3) << 4;       // 16 cols = 32B per lane
#pragma unroll
            for (int half = 0; half < 2; half++) {
                int r2 = (half << 4) + row;
                int ch0 = ((c0 >> 3) ^ (r2 & 7)) << 3;
                int ch1 = (((c0 + 8) >> 3) ^ (r2 & 7)) << 3;
                bf16x8 v0 = *(const bf16x8*)(qb + r2 * 64 + ch0);
                bf16x8 v1 = *(const bf16x8*)(qb + r2 * 64 + ch1);
                long gaddr = (long)(m0 + (wv << 5) + r2) * 576 + j * 64 + c0;
                *(bf16x8*)(out + gaddr) = v0;
                *(bf16x8*)(out + gaddr + 8) = v1;
            }
        }
        __syncthreads();
    }
}

// ---------------- A-in-regs GEMM with full W in LDS (K=192, N=192) ----------------
// MODE 3: proj -> window-reverse+roll, resid += v
// MODE 4: pointwise conv -> BN + ReLU, f32 channel-major out
template <int MODE>
__global__ __launch_bounds__(256) void wk_k(const short* __restrict__ A,
                                            const short* __restrict__ Wg,  // (192,192)
                                            const float* __restrict__ bias,
                                            float* __restrict__ resid, float* __restrict__ outF,
                                            const float* __restrict__ bng,
                                            const float* __restrict__ bnb, int shift) {
    __shared__ short Ws[36864];
    const int tid = threadIdx.x;
    const int wv = tid >> 6, lane = tid & 63;
    const int lr = lane & 15, lg = lane >> 4;
    const int mt = ((blockIdx.x & 7) << 6) + (blockIdx.x >> 3);  // 512 blocks
    const int m0 = mt << 7;

    bf16x8 areg[2][6];
#pragma unroll
    for (int mf = 0; mf < 2; mf++)
#pragma unroll
        for (int kk = 0; kk < 6; kk++)
            areg[mf][kk] = *(const bf16x8*)(A + (long)(m0 + (wv << 5) + (mf << 4) + lr) * 192 + kk * 32 + (lg << 3));

#pragma unroll
    for (int q = 0; q < 18; q++) {
        int base = (wv * 18 + q) * 512;
        int E = base + lane * 8;
        int row = E / 192;
        int cb = (E - row * 192) >> 3;
        gload_lds16(Wg + (long)row * 192 + ((cb ^ (row & 7)) << 3), Ws + base);
    }
    __syncthreads();

    f32x4 acc[2][12] = {};
#pragma unroll
    for (int kk = 0; kk < 6; kk++) {
        int cb = (kk << 2) + lg;
#pragma unroll
        for (int njb = 0; njb < 3; njb++) {
            bf16x8 wf[4];
#pragma unroll
            for (int q = 0; q < 4; q++) {
                int r = ((njb * 4 + q) << 4) + lr;
                wf[q] = *(const bf16x8*)(Ws + r * 192 + ((cb ^ (r & 7)) << 3));
            }
#pragma unroll
            for (int mf = 0; mf < 2; mf++)
#pragma unroll
                for (int q = 0; q < 4; q++)
                    acc[mf][njb * 4 + q] = __builtin_amdgcn_mfma_f32_16x16x32_bf16(
                        areg[mf][kk], wf[q], acc[mf][njb * 4 + q], 0, 0, 0);
        }
    }

#pragma unroll
    for (int mf = 0; mf < 2; mf++) {
        int rbase = m0 + (wv << 5) + (mf << 4) + (lg << 2);
#pragma unroll
        for (int nj = 0; nj < 12; nj++) {
            int col = (nj << 4) + lr;
            float bv = bias[col];
            if (MODE == 4) {
                float sc = 0.9999950000374997f * bng[col];
                float bb = bnb[col];
                f32x4 o;
#pragma unroll
                for (int e = 0; e < 4; e++) {
                    float v = (acc[mf][nj][e] + bv) * sc + bb;
                    o[e] = v > 0.f ? v : 0.f;
                }
                int b = rbase >> 15, l = rbase & 32767;
                *(f32x4*)(outF + ((long)(b * 192 + col) << 15) + l) = o;
            } else {  // MODE 3
#pragma unroll
                for (int e = 0; e < 4; e++) {
                    int r = rbase + e;
                    int b = r >> 15, rr = r & 32767, widx = rr >> 6, n = rr & 63;
                    int wh = widx >> 6, ww = (widx >> 3) & 7, wt = widx & 7;
                    int ih = n >> 4, iw = (n >> 2) & 3, it = n & 3;
                    int h = ((wh << 2) + ih + shift) & 31;
                    int w = ((ww << 2) + iw + shift) & 31;
                    int t = ((wt << 2) + it + shift) & 31;
                    long tok = (long)(b << 15) + (h << 10) + (w << 5) + t;
                    resid[tok * 192 + col] += acc[mf][nj][e] + bv;
                }
            }
        }
    }
}

// ---------------- fused LN2+MLP v5 (round-7 proven 73us config, restored) ----------------
__global__ __launch_bounds__(512, 2) void mlp_k(const float* __restrict__ XF,
                                                const short* __restrict__ W1g,  // fc1T (768,192)
                                                const short* __restrict__ W2g,  // fc2T (192,768)
                                                const float* __restrict__ b1,
                                                const float* __restrict__ b2,
                                                const float* __restrict__ n2g,
                                                const float* __restrict__ n2b,
                                                float* __restrict__ resid) {
    __shared__ short Wbuf[2][24576];  // per buf: W1 64x192 @0, W2 192x64 @12288
    __shared__ short Hs[16384];       // 8 waves x 32x64 (XOR-swizzled)
    const int tid = threadIdx.x;
    const int wv = tid >> 6, lane = tid & 63;
    const int lr = lane & 15, lg = lane >> 4;
    const int mt = ((blockIdx.x & 7) << 5) + (blockIdx.x >> 3);  // XCD swizzle, 256 blocks
    const int m0 = mt << 8;
    short* hw = Hs + (wv << 11);  // wave-private 32x64

    bf16x8 areg[2][6];
#pragma unroll
    for (int mf = 0; mf < 2; mf++) {
        const float* rp = XF + (long)(m0 + (wv << 5) + (mf << 4) + lr) * 192;
        f32x4 xv[6][2];
        float s = 0.f, sq = 0.f;
#pragma unroll
        for (int kk = 0; kk < 6; kk++)
#pragma unroll
            for (int q = 0; q < 2; q++) {
                xv[kk][q] = *(const f32x4*)(rp + kk * 32 + (lg << 3) + q * 4);
#pragma unroll
                for (int e = 0; e < 4; e++) {
                    s += xv[kk][q][e];
                    sq += xv[kk][q][e] * xv[kk][q][e];
                }
            }
        s += __shfl_xor(s, 16, 64); s += __shfl_xor(s, 32, 64);
        sq += __shfl_xor(sq, 16, 64); sq += __shfl_xor(sq, 32, 64);
        float mu = s * (1.f / 192.f);
        float var = sq * (1.f / 192.f) - mu * mu;
        float rstd = rsqrtf(var + 1e-5f);
#pragma unroll
        for (int kk = 0; kk < 6; kk++) {
            int cb = kk * 32 + (lg << 3);
            f32x4 g0 = *(const f32x4*)(n2g + cb), g1 = *(const f32x4*)(n2g + cb + 4);
            f32x4 b0 = *(const f32x4*)(n2b + cb), b1v = *(const f32x4*)(n2b + cb + 4);
            bf16x8 t;
#pragma unroll
            for (int e = 0; e < 4; e++) {
                t[e] = f2bf((xv[kk][0][e] - mu) * rstd * g0[e] + b0[e]);
                t[e + 4] = f2bf((xv[kk][1][e] - mu) * rstd * g1[e] + b1v[e]);
            }
            areg[mf][kk] = t;
        }
    }

    auto stage = [&](int jc, int buf) {
#pragma unroll
        for (int q = 0; q < 3; q++) {  // W1 chunk: 64x192
            int base = (wv * 3 + q) * 512;
            int E = base + lane * 8;
            int row = E / 192;
            int cb = (E - row * 192) >> 3;
            gload_lds16(W1g + (long)(jc * 64 + row) * 192 + ((cb ^ (row & 7)) << 3),
                        &Wbuf[buf][base]);
        }
#pragma unroll
        for (int q = 0; q < 3; q++) {  // W2 chunk: 192x64
            int base = (wv * 3 + q) * 512;
            int E = base + lane * 8;
            int row = E >> 6;
            int cb = (E & 63) >> 3;
            gload_lds16(W2g + (long)row * 768 + jc * 64 + ((cb ^ (row & 7)) << 3),
                        &Wbuf[buf][12288 + base]);
        }
    };

    stage(0, 0);
    __syncthreads();

    f32x4 acc[2][12] = {};

    for (int j = 0; j < 12; j++) {
        if (j < 11) stage(j + 1, (j + 1) & 1);
        const short* W1s = Wbuf[j & 1];
        const short* W2s = Wbuf[j & 1] + 12288;

        f32x4 hacc[4][2] = {};
#pragma unroll
        for (int kk = 0; kk < 6; kk++) {
            int cb = (kk << 2) + lg;
            bf16x8 wf[4];
#pragma unroll
            for (int hf = 0; hf < 4; hf++) {
                int r = (hf << 4) + lr;
                wf[hf] = *(const bf16x8*)(W1s + r * 192 + ((cb ^ (r & 7)) << 3));
            }
#pragma unroll
            for (int hf = 0; hf < 4; hf++)
#pragma unroll
                for (int mf = 0; mf < 2; mf++)
                    hacc[hf][mf] = __builtin_amdgcn_mfma_f32_16x16x32_bf16(
                        wf[hf], areg[mf][kk], hacc[hf][mf], 0, 0, 0);
        }

#pragma unroll
        for (int hf = 0; hf < 4; hf++) {
            f32x4 bv = *(const f32x4*)(b1 + j * 64 + (hf << 4) + (lg << 2));
#pragma unroll
            for (int mf = 0; mf < 2; mf++) {
                s16x4 hv;
#pragma unroll
                for (int e = 0; e < 4; e++) {
                    float v = hacc[hf][mf][e] + bv[e];
                    float inner = fmaf(-0.07135481627f, v * v, -1.595769122f);
                    float eterm = __expf(v * inner);  // exp(-2u)
                    float gl = v * __builtin_amdgcn_rcpf(1.f + eterm);
                    hv[e] = f2bf(gl);
                }
                int Mrow = (mf << 4) + lr;
                int blk = (hf << 1) | (lg >> 1);
                *(s16x4*)(hw + Mrow * 64 + ((blk ^ (Mrow & 7)) << 3) + ((lg & 1) << 2)) = hv;
            }
        }
        asm volatile("s_waitcnt lgkmcnt(0)" ::: "memory");

#pragma unroll
        for (int kk = 0; kk < 2; kk++) {
            int cb = (kk << 2) + lg;
            bf16x8 ah[2], bw[12];
#pragma unroll
            for (int mf = 0; mf < 2; mf++) {
                int r = (mf << 4) + lr;
                ah[mf] = *(const bf16x8*)(hw + r * 64 + ((cb ^ (r & 7)) << 3));
            }
#pragma unroll
            for (int nj = 0; nj < 12; nj++) {
                int r = (nj << 4) + lr;
                bw[nj] = *(const bf16x8*)(W2s + r * 64 + ((cb ^ (r & 7)) << 3));
            }
#pragma unroll
            for (int mf = 0; mf < 2; mf++)
#pragma unroll
                for (int nj = 0; nj < 12; nj++)
                    acc[mf][nj] = __builtin_amdgcn_mfma_f32_16x16x32_bf16(
                        ah[mf], bw[nj], acc[mf][nj], 0, 0, 0);
        }
        __syncthreads();
    }

#pragma unroll
    for (int mf = 0; mf < 2; mf++) {
        int rbase = m0 + (wv << 5) + (mf << 4) + (lg << 2);
#pragma unroll
        for (int nj = 0; nj < 12; nj++) {
            int col = (nj << 4) + lr;
            float bv = b2[col];
#pragma unroll
            for (int e = 0; e < 4; e++) {
                long r = rbase + e;
                resid[r * 192 + col] += acc[mf][nj][e] + bv;
            }
        }
    }
}

// ---------------- windowed attention: one wave per (window, head) ----------------
__global__ __launch_bounds__(256) void attn_k(const short* __restrict__ qkv,
                                              const float* __restrict__ rpb,  // (343,6)
                                              short* __restrict__ o, int shifted) {
    __shared__ short lds[4 * 6144];
    const int wv = threadIdx.x >> 6, lane = threadIdx.x & 63;
    short* vT = lds + wv * 6144;
    short* P = lds + wv * 6144 + 2048;
    const int task = blockIdx.x * 4 + wv;
    const int win = task / 6, head = task - win * 6;
    const int lr = lane & 15, lg = lane >> 4;
    const long qbase = (long)win * 64 * 576 + head * 32;

    bf16x8 aq[4], bk[4];
#pragma unroll
    for (int bi = 0; bi < 4; bi++)
        aq[bi] = *(const bf16x8*)(qkv + qbase + (long)((bi << 4) + lr) * 576 + (lg << 3));
#pragma unroll
    for (int bj = 0; bj < 4; bj++)
        bk[bj] = *(const bf16x8*)(qkv + qbase + 192 + (long)((bj << 4) + lr) * 576 + (lg << 3));
    f32x4 s[4][4] = {};
#pragma unroll
    for (int bi = 0; bi < 4; bi++)
#pragma unroll
        for (int bj = 0; bj < 4; bj++)
            s[bi][bj] = __builtin_amdgcn_mfma_f32_16x16x32_bf16(aq[bi], bk[bj], s[bi][bj], 0, 0, 0);

#pragma unroll
    for (int j = 0; j < 4; j++) {
        bf16x8 vv = *(const bf16x8*)(qkv + qbase + 384 + (long)lane * 576 + (j << 3));
#pragma unroll
        for (int e = 0; e < 8; e++) {
            int d = (j << 3) + e;
            vT[d * 64 + (((lane >> 3) ^ (d & 7)) << 3) + (lane & 7)] = vv[e];
        }
    }

    const float SCALE = 0.17677669529663687f;
    int widx = win & 511;
    int wh = widx >> 6, ww = (widx >> 3) & 7, wt = widx & 7;
    int ihm[4], iwm[4], itm[4], lblm[4];
#pragma unroll
    for (int bj = 0; bj < 4; bj++) {
        int m = (bj << 4) + lr;
        ihm[bj] = m >> 4; iwm[bj] = (m >> 2) & 3; itm[bj] = m & 3;
        lblm[bj] = reg3((wh << 2) + ihm[bj]) * 9 + reg3((ww << 2) + iwm[bj]) * 3 + reg3((wt << 2) + itm[bj]);
    }
#pragma unroll
    for (int bi = 0; bi < 4; bi++) {
#pragma unroll
        for (int e = 0; e < 4; e++) {
            int n = (bi << 4) + (lg << 2) + e;
            int ihn = n >> 4, iwn = (n >> 2) & 3, itn = n & 3;
            int lbln = reg3((wh << 2) + ihn) * 9 + reg3((ww << 2) + iwn) * 3 + reg3((wt << 2) + itn);
#pragma unroll
            for (int bj = 0; bj < 4; bj++) {
                int idx = (ihn - ihm[bj] + 3) * 49 + (iwn - iwm[bj] + 3) * 7 + (itn - itm[bj] + 3);
                float bias = rpb[idx * 6 + head];
                float val = s[bi][bj][e] * SCALE + bias;
                if (shifted && lbln != lblm[bj]) val -= 100.f;
                s[bi][bj][e] = val;
            }
        }
    }

#pragma unroll
    for (int bi = 0; bi < 4; bi++) {
#pragma unroll
        for (int e = 0; e < 4; e++) {
            float mx = s[bi][0][e];
#pragma unroll
            for (int bj = 1; bj < 4; bj++) mx = fmaxf(mx, s[bi][bj][e]);
#pragma unroll
            for (int off = 1; off < 16; off <<= 1) mx = fmaxf(mx, __shfl_xor(mx, off, 64));
            float sm = 0.f;
#pragma unroll
            for (int bj = 0; bj < 4; bj++) {
                float p = __expf(s[bi][bj][e] - mx);
                s[bi][bj][e] = p;
                sm += p;
            }
#pragma unroll
            for (int off = 1; off < 16; off <<= 1) sm += __shfl_xor(sm, off, 64);
            float rinv = 1.f / sm;
            int n = (bi << 4) + (lg << 2) + e;
#pragma unroll
            for (int bj = 0; bj < 4; bj++) {
                int m = (bj << 4) + lr;
                P[n * 64 + (((m >> 3) ^ (n & 7)) << 3) + (m & 7)] = f2bf(s[bi][bj][e] * rinv);
            }
        }
    }

    f32x4 oacc[4][2] = {};
#pragma unroll
    for (int ks = 0; ks < 2; ks++) {
        bf16x8 ap[4], bv2[2];
        int kb = (ks << 2) + lg;
#pragma unroll
        for (int bi = 0; bi < 4; bi++) {
            int r = (bi << 4) + lr;
            ap[bi] = *(const bf16x8*)(P + r * 64 + ((kb ^ (r & 7)) << 3));
        }
#pragma unroll
        for (int nf = 0; nf < 2; nf++) {
            int d = (nf << 4) + lr;
            bv2[nf] = *(const bf16x8*)(vT + d * 64 + ((kb ^ (d & 7)) << 3));
        }
#pragma unroll
        for (int bi = 0; bi < 4; bi++)
#pragma unroll
            for (int nf = 0; nf < 2; nf++)
                oacc[bi][nf] = __builtin_amdgcn_mfma_f32_16x16x32_bf16(ap[bi], bv2[nf], oacc[bi][nf], 0, 0, 0);
    }

    // ---- output bounce through P region (free after PV): 64x32 swizzled ----
#pragma unroll
    for (int bi = 0; bi < 4; bi++)
#pragma unroll
        for (int nf = 0; nf < 2; nf++)
#pragma unroll
            for (int e = 0; e < 4; e++) {
                int n = (bi << 4) + (lg << 2) + e;
                int d = (nf << 4) + lr;
                int cc = ((((d >> 3) ^ (n & 3)) << 3)) | (d & 7);
                P[n * 32 + cc] = f2bf(oacc[bi][nf][e]);
            }
    asm volatile("s_waitcnt lgkmcnt(0)" ::: "memory");
#pragma unroll
    for (int q = 0; q < 4; q++) {
        int n = (q << 4) + (lane >> 2);
        int c0 = (lane & 3) << 3;  // 8 cols = 16B per lane, 4 lanes/row = 64B run
        int ch = ((c0 >> 3) ^ (n & 3)) << 3;
        bf16x8 v = *(const bf16x8*)(P + n * 32 + ch);
        *(bf16x8*)(o + ((long)win * 64 + n) * 192 + head * 32 + c0) = v;
    }
}

// ---------------- depthwise 3x3x3 conv, register-blocked along t ----------------
__global__ __launch_bounds__(192) void dw_k(const float* __restrict__ xf,
                                            const float* __restrict__ w,
                                            const float* __restrict__ db,
                                            short* __restrict__ out) {
    int c = threadIdx.x;
    int blk = blockIdx.x;
    int t0 = (blk & 3) << 3;
    int bhw = blk >> 2;
    int b = bhw >> 10, h = (bhw >> 5) & 31, wq = bhw & 31;

    float wr[27];
#pragma unroll
    for (int k = 0; k < 27; k++) wr[k] = w[c * 27 + k];
    float bias = db[c];
    float acc[8];
#pragma unroll
    for (int j = 0; j < 8; j++) acc[j] = bias;

#pragma unroll
    for (int a = 0; a < 3; a++) {
        int hh = h + a - 1;
        if (hh < 0 || hh > 31) continue;
#pragma unroll
        for (int bb = 0; bb < 3; bb++) {
            int ww = wq + bb - 1;
            if (ww < 0 || ww > 31) continue;
            const float* base = xf + ((long)(b << 15) + (hh << 10) + (ww << 5)) * 192 + c;
            float val[10];
#pragma unroll
            for (int tt = 0; tt < 10; tt++) {
                int t = t0 + tt - 1;
                val[tt] = (t >= 0 && t < 32) ? base[t * 192] : 0.f;
            }
#pragma unroll
            for (int d = 0; d < 3; d++) {
                float wv = wr[a * 9 + bb * 3 + d];
#pragma unroll
                for (int j = 0; j < 8; j++)
                    acc[j] = fmaf(val[j + d], wv, acc[j]);
            }
        }
    }
    long obase = ((long)(b << 15) + (h << 10) + (wq << 5) + t0) * 192 + c;
#pragma unroll
    for (int j = 0; j < 8; j++) out[obase + j * 192] = f2bf(acc[j]);
}

// ---------------- launch ----------------
extern "C" void kernel_launch(void* const* d_in, const int* in_sizes, int n_in,
                              void* d_out, int out_size, void* d_ws, size_t ws_size,
                              hipStream_t stream) {
    const float* x      = (const float*)d_in[0];
    const float* n1g    = (const float*)d_in[1];
    const float* n1b    = (const float*)d_in[2];
    const float* qkv_w  = (const float*)d_in[3];
    const float* qkv_b  = (const float*)d_in[4];
    const float* rpb    = (const float*)d_in[5];
    const float* proj_w = (const float*)d_in[6];
    const float* proj_b = (const float*)d_in[7];
    const float* n2g    = (const float*)d_in[8];
    const float* n2b    = (const float*)d_in[9];
    const float* fc1_w  = (const float*)d_in[10];
    const float* fc1_b  = (const float*)d_in[11];
    const float* fc2_w  = (const float*)d_in[12];
    const float* fc2_b  = (const float*)d_in[13];
    const float* dw_w   = (const float*)d_in[14];
    const float* dw_b   = (const float*)d_in[15];
    const float* pw_w   = (const float*)d_in[16];
    const float* pw_b   = (const float*)d_in[17];
    const float* bn_g   = (const float*)d_in[18];
    const float* bn_b   = (const float*)d_in[19];
    float* outF = (float*)d_out;

    char* ws = (char*)d_ws;
    float* XF = (float*)ws;
    short* Abuf = (short*)(ws + 50331648);
    short* Bbuf = (short*)(ws + 150994944);
    short* WT = (short*)(ws + 226492416);

    transpose_in<<<dim3(1024, 6, 2), dim3(32, 8), 0, stream>>>(x, XF);
    prep_w<<<7056, 256, 0, stream>>>(qkv_w, proj_w, fc1_w, fc2_w, pw_w, WT);

    for (int i = 0; i < 4; i++) {
        int shifted = i & 1;
        int shift = shifted ? 2 : 0;
        qkv_k<<<512, 256, 0, stream>>>(XF, WT + (long)i * 442368, qkv_b + i * 576,
                                       n1g + i * 192, n1b + i * 192, Bbuf, shift);
        attn_k<<<1536, 256, 0, stream>>>(Bbuf, rpb + i * 2058, Abuf, shifted);
        wk_k<3><<<512, 256, 0, stream>>>(Abuf, WT + (long)i * 442368 + 110592, proj_b + i * 192,
                                         XF, nullptr, nullptr, nullptr, shift);
        mlp_k<<<256, 512, 0, stream>>>(XF, WT + (long)i * 442368 + 147456,
                                       WT + (long)i * 442368 + 294912,
                                       fc1_b + i * 768, fc2_b + i * 192,
                                       n2g + i * 192, n2b + i * 192, XF);
    }

    dw_k<<<8192, 192, 0, stream>>>(XF, dw_w, dw_b, Abuf);
    wk_k<4><<<512, 256, 0, stream>>>(Abuf, WT + 1769472, pw_b,
                                     nullptr, outF, bn_g, bn_b, 0);
}

// Round 14
// 766.606 us; speedup vs baseline: 1.0986x; 1.0358x over previous
//
#include <hip/hip_runtime.h>
#include <hip/hip_bf16.h>

// ---------------- constants ----------------
// C=192, H=W=T=32, WS=4, SS=2, NH=6, HD=32, N=64 tokens/window
// L = 32768 tokens/batch, B=2 -> M = 65536 rows everywhere.
#define DI __device__ __forceinline__

typedef short bf16x8 __attribute__((ext_vector_type(8)));
typedef float f32x4 __attribute__((ext_vector_type(4)));
typedef short s16x4 __attribute__((ext_vector_type(4)));

DI short f2bf(float f) {
    __hip_bfloat16 h = __float2bfloat16(f);
    return *reinterpret_cast<short*>(&h);
}

DI void gload_lds16(const short* gsrc, short* ldst) {
    __builtin_amdgcn_global_load_lds(
        (const __attribute__((address_space(1))) void*)gsrc,
        (__attribute__((address_space(3))) void*)ldst, 16, 0, 0);
}

// region label along one axis for the shift mask: [0,28)->0, [28,30)->1, [30,32)->2
DI int reg3(int p) { return p < 28 ? 0 : (p < 30 ? 1 : 2); }

// ---------------- input transpose: x (B,C,L) -> xf (B,L,C) f32 ----------------
__global__ __launch_bounds__(256) void transpose_in(const float* __restrict__ x,
                                                    float* __restrict__ xf) {
    __shared__ float tile[32][33];
    int b = blockIdx.z;
    int c0 = blockIdx.y * 32;
    int l0 = blockIdx.x * 32;
    int tx = threadIdx.x, ty = threadIdx.y;  // 32 x 8
#pragma unroll
    for (int i = 0; i < 32; i += 8)
        tile[ty + i][tx] = x[(long)(b * 192 + c0 + ty + i) * 32768 + l0 + tx];
    __syncthreads();
#pragma unroll
    for (int i = 0; i < 32; i += 8)
        xf[(long)(b * 32768 + l0 + ty + i) * 192 + c0 + tx] = tile[tx][ty + i];
}

// ---------------- weight prep ----------------
__global__ __launch_bounds__(256) void prep_w(const float* __restrict__ qkv_w,
                                              const float* __restrict__ proj_w,
                                              const float* __restrict__ fc1_w,
                                              const float* __restrict__ fc2_w,
                                              const float* __restrict__ pw_w,
                                              short* __restrict__ wt) {
    int i = blockIdx.x * 256 + threadIdx.x;
    float v;
    if (i < 1769472) {
        int b4 = i / 442368, r = i - b4 * 442368;
        if (r < 110592) { int n = r / 192, k = r - n * 192; v = qkv_w[b4 * 110592 + k * 576 + n]; }
        else if (r < 147456) { int r2 = r - 110592; int n = r2 / 192, k = r2 - n * 192; v = proj_w[b4 * 36864 + k * 192 + n]; }
        else if (r < 294912) { int r2 = r - 147456; int n = r2 / 192, k = r2 - n * 192; v = fc1_w[b4 * 147456 + k * 768 + n]; }
        else { int r2 = r - 294912; int n = r2 / 768, k = r2 - n * 768; v = fc2_w[b4 * 147456 + k * 192 + n]; }
        wt[i] = f2bf(v);
    } else {
        int r = i - 1769472;
        wt[i] = f2bf(pw_w[r]);
    }
}

// ---------------- fused LN1 + QKV: out = LN(gather(x)) @ Wqkv + b ----------------
// Swapped-operand MFMA -> lane holds (row, 4 consecutive cols) -> packed 8B stores.
__global__ __launch_bounds__(256) void qkv_k(const float* __restrict__ XF,
                                             const short* __restrict__ Wg,  // qkvT (576,192)
                                             const float* __restrict__ bias,
                                             const float* __restrict__ n1g,
                                             const float* __restrict__ n1b,
                                             short* __restrict__ out, int shift) {
    __shared__ short Ws[2][12288];
    const int tid = threadIdx.x;
    const int wv = tid >> 6, lane = tid & 63;
    const int lr = lane & 15, lg = lane >> 4;
    const int mt = ((blockIdx.x & 7) << 6) + (blockIdx.x >> 3);  // XCD swizzle, 512 blocks
    const int m0 = mt << 7;

    // ---- LN1 prologue with roll+window-partition gather ----
    bf16x8 areg[2][6];
#pragma unroll
    for (int mf = 0; mf < 2; mf++) {
        int row = m0 + (wv << 5) + (mf << 4) + lr;
        int b = row >> 15, r = row & 32767, widx = r >> 6, n = r & 63;
        int wh = widx >> 6, ww = (widx >> 3) & 7, wt = widx & 7;
        int ih = n >> 4, iw = (n >> 2) & 3, it = n & 3;
        int h = ((wh << 2) + ih + shift) & 31;
        int w = ((ww << 2) + iw + shift) & 31;
        int t = ((wt << 2) + it + shift) & 31;
        const float* rp = XF + ((long)(b << 15) + (h << 10) + (w << 5) + t) * 192;
        f32x4 xv[6][2];
        float s = 0.f, sq = 0.f;
#pragma unroll
        for (int kk = 0; kk < 6; kk++)
#pragma unroll
            for (int q = 0; q < 2; q++) {
                xv[kk][q] = *(const f32x4*)(rp + kk * 32 + (lg << 3) + q * 4);
#pragma unroll
                for (int e = 0; e < 4; e++) {
                    s += xv[kk][q][e];
                    sq += xv[kk][q][e] * xv[kk][q][e];
                }
            }
        s += __shfl_xor(s, 16, 64); s += __shfl_xor(s, 32, 64);
        sq += __shfl_xor(sq, 16, 64); sq += __shfl_xor(sq, 32, 64);
        float mu = s * (1.f / 192.f);
        float var = sq * (1.f / 192.f) - mu * mu;
        float rstd = rsqrtf(var + 1e-5f);
#pragma unroll
        for (int kk = 0; kk < 6; kk++) {
            int cb = kk * 32 + (lg << 3);
            f32x4 g0 = *(const f32x4*)(n1g + cb), g1 = *(const f32x4*)(n1g + cb + 4);
            f32x4 b0 = *(const f32x4*)(n1b + cb), b1v = *(const f32x4*)(n1b + cb + 4);
            bf16x8 tt;
#pragma unroll
            for (int e = 0; e < 4; e++) {
                tt[e] = f2bf((xv[kk][0][e] - mu) * rstd * g0[e] + b0[e]);
                tt[e + 4] = f2bf((xv[kk][1][e] - mu) * rstd * g1[e] + b1v[e]);
            }
            areg[mf][kk] = tt;
        }
    }

    auto stage = [&](int jc, int buf) {
#pragma unroll
        for (int q = 0; q < 6; q++) {
            int base = (wv * 6 + q) * 512;
            int E = base + lane * 8;
            int row = E / 192;
            int cb = (E - row * 192) >> 3;
            gload_lds16(Wg + (long)(jc * 64 + row) * 192 + ((cb ^ (row & 7)) << 3),
                        &Ws[buf][base]);
        }
    };

    stage(0, 0);
    __syncthreads();

    for (int j = 0; j < 9; j++) {
        if (j < 8) stage(j + 1, (j + 1) & 1);
        const short* W = Ws[j & 1];
        f32x4 acc[2][4] = {};
#pragma unroll
        for (int kk = 0; kk < 6; kk++) {
            int cb = (kk << 2) + lg;
            bf16x8 wf[4];
#pragma unroll
            for (int nf = 0; nf < 4; nf++) {
                int r = (nf << 4) + lr;
                wf[nf] = *(const bf16x8*)(W + r * 192 + ((cb ^ (r & 7)) << 3));
            }
            // swapped operands: lane = M-row (areg as B), regs = cols (wf as A)
#pragma unroll
            for (int mf = 0; mf < 2; mf++)
#pragma unroll
                for (int nf = 0; nf < 4; nf++)
                    acc[mf][nf] = __builtin_amdgcn_mfma_f32_16x16x32_bf16(
                        wf[nf], areg[mf][kk], acc[mf][nf], 0, 0, 0);
        }
        // packed 8B stores: lane owns row m0+(wv<<5)+(mf<<4)+lr, cols (nf<<4)+(lg<<2)..+3
#pragma unroll
        for (int mf = 0; mf < 2; mf++) {
            long rbase = (long)(m0 + (wv << 5) + (mf << 4) + lr) * 576 + j * 64;
#pragma unroll
            for (int nf = 0; nf < 4; nf++) {
                int col = (nf << 4) + (lg << 2);
                f32x4 bv = *(const f32x4*)(bias + j * 64 + col);
                s16x4 pk;
#pragma unroll
                for (int e = 0; e < 4; e++) pk[e] = f2bf(acc[mf][nf][e] + bv[e]);
                *(s16x4*)(out + rbase + col) = pk;
            }
        }
        __syncthreads();
    }
}

// ---------------- A-in-regs GEMM with full W in LDS (K=192, N=192) ----------------
// MODE 3: proj (swapped operands) -> window-reverse+roll, f32x4 resid RMW
// MODE 4: pointwise conv (unswapped) -> BN + ReLU, f32 channel-major out
template <int MODE>
__global__ __launch_bounds__(256) void wk_k(const short* __restrict__ A,
                                            const short* __restrict__ Wg,  // (192,192)
                                            const float* __restrict__ bias,
                                            float* __restrict__ resid, float* __restrict__ outF,
                                            const float* __restrict__ bng,
                                            const float* __restrict__ bnb, int shift) {
    __shared__ short Ws[36864];
    const int tid = threadIdx.x;
    const int wv = tid >> 6, lane = tid & 63;
    const int lr = lane & 15, lg = lane >> 4;
    const int mt = ((blockIdx.x & 7) << 6) + (blockIdx.x >> 3);  // 512 blocks
    const int m0 = mt << 7;

    bf16x8 areg[2][6];
#pragma unroll
    for (int mf = 0; mf < 2; mf++)
#pragma unroll
        for (int kk = 0; kk < 6; kk++)
            areg[mf][kk] = *(const bf16x8*)(A + (long)(m0 + (wv << 5) + (mf << 4) + lr) * 192 + kk * 32 + (lg << 3));

#pragma unroll
    for (int q = 0; q < 18; q++) {
        int base = (wv * 18 + q) * 512;
        int E = base + lane * 8;
        int row = E / 192;
        int cb = (E - row * 192) >> 3;
        gload_lds16(Wg + (long)row * 192 + ((cb ^ (row & 7)) << 3), Ws + base);
    }
    __syncthreads();

    f32x4 acc[2][12] = {};
#pragma unroll
    for (int kk = 0; kk < 6; kk++) {
        int cb = (kk << 2) + lg;
#pragma unroll
        for (int njb = 0; njb < 3; njb++) {
            bf16x8 wf[4];
#pragma unroll
            for (int q = 0; q < 4; q++) {
                int r = ((njb * 4 + q) << 4) + lr;
                wf[q] = *(const bf16x8*)(Ws + r * 192 + ((cb ^ (r & 7)) << 3));
            }
#pragma unroll
            for (int mf = 0; mf < 2; mf++)
#pragma unroll
                for (int q = 0; q < 4; q++) {
                    if (MODE == 3)
                        acc[mf][njb * 4 + q] = __builtin_amdgcn_mfma_f32_16x16x32_bf16(
                            wf[q], areg[mf][kk], acc[mf][njb * 4 + q], 0, 0, 0);
                    else
                        acc[mf][njb * 4 + q] = __builtin_amdgcn_mfma_f32_16x16x32_bf16(
                            areg[mf][kk], wf[q], acc[mf][njb * 4 + q], 0, 0, 0);
                }
        }
    }

    if (MODE == 3) {
        // swapped: lane owns row (mf<<4)+lr, cols (nj<<4)+(lg<<2)..+3 -> f32x4 RMW
#pragma unroll
        for (int mf = 0; mf < 2; mf++) {
            int r = m0 + (wv << 5) + (mf << 4) + lr;
            int b = r >> 15, rr = r & 32767, widx = rr >> 6, n = rr & 63;
            int wh = widx >> 6, ww = (widx >> 3) & 7, wt = widx & 7;
            int ih = n >> 4, iw = (n >> 2) & 3, it = n & 3;
            int h = ((wh << 2) + ih + shift) & 31;
            int w = ((ww << 2) + iw + shift) & 31;
            int t = ((wt << 2) + it + shift) & 31;
            long tok = (long)(b << 15) + (h << 10) + (w << 5) + t;
            float* rp = resid + tok * 192;
#pragma unroll
            for (int nj = 0; nj < 12; nj++) {
                int col = (nj << 4) + (lg << 2);
                f32x4 bv = *(const f32x4*)(bias + col);
                f32x4 cur = *(f32x4*)(rp + col);
#pragma unroll
                for (int e = 0; e < 4; e++) cur[e] += acc[mf][nj][e] + bv[e];
                *(f32x4*)(rp + col) = cur;
            }
        }
    } else {
#pragma unroll
        for (int mf = 0; mf < 2; mf++) {
            int rbase = m0 + (wv << 5) + (mf << 4) + (lg << 2);
#pragma unroll
            for (int nj = 0; nj < 12; nj++) {
                int col = (nj << 4) + lr;
                float bv = bias[col];
                float sc = 0.9999950000374997f * bng[col];
                float bb = bnb[col];
                f32x4 o;
#pragma unroll
                for (int e = 0; e < 4; e++) {
                    float v = (acc[mf][nj][e] + bv) * sc + bb;
                    o[e] = v > 0.f ? v : 0.f;
                }
                int b = rbase >> 15, l = rbase & 32767;
                *(f32x4*)(outF + ((long)(b * 192 + col) << 15) + l) = o;
            }
        }
    }
}

// ---------------- fused LN2+MLP v5 (proven 73us config) ----------------
__global__ __launch_bounds__(512, 2) void mlp_k(const float* __restrict__ XF,
                                                const short* __restrict__ W1g,  // fc1T (768,192)
                                                const short* __restrict__ W2g,  // fc2T (192,768)
                                                const float* __restrict__ b1,
                                                const float* __restrict__ b2,
                                                const float* __restrict__ n2g,
                                                const float* __restrict__ n2b,
                                                float* __restrict__ resid) {
    __shared__ short Wbuf[2][24576];  // per buf: W1 64x192 @0, W2 192x64 @12288
    __shared__ short Hs[16384];       // 8 waves x 32x64 (XOR-swizzled)
    const int tid = threadIdx.x;
    const int wv = tid >> 6, lane = tid & 63;
    const int lr = lane & 15, lg = lane >> 4;
    const int mt = ((blockIdx.x & 7) << 5) + (blockIdx.x >> 3);  // XCD swizzle, 256 blocks
    const int m0 = mt << 8;
    short* hw = Hs + (wv << 11);  // wave-private 32x64

    bf16x8 areg[2][6];
#pragma unroll
    for (int mf = 0; mf < 2; mf++) {
        const float* rp = XF + (long)(m0 + (wv << 5) + (mf << 4) + lr) * 192;
        f32x4 xv[6][2];
        float s = 0.f, sq = 0.f;
#pragma unroll
        for (int kk = 0; kk < 6; kk++)
#pragma unroll
            for (int q = 0; q < 2; q++) {
                xv[kk][q] = *(const f32x4*)(rp + kk * 32 + (lg << 3) + q * 4);
#pragma unroll
                for (int e = 0; e < 4; e++) {
                    s += xv[kk][q][e];
                    sq += xv[kk][q][e] * xv[kk][q][e];
                }
            }
        s += __shfl_xor(s, 16, 64); s += __shfl_xor(s, 32, 64);
        sq += __shfl_xor(sq, 16, 64); sq += __shfl_xor(sq, 32, 64);
        float mu = s * (1.f / 192.f);
        float var = sq * (1.f / 192.f) - mu * mu;
        float rstd = rsqrtf(var + 1e-5f);
#pragma unroll
        for (int kk = 0; kk < 6; kk++) {
            int cb = kk * 32 + (lg << 3);
            f32x4 g0 = *(const f32x4*)(n2g + cb), g1 = *(const f32x4*)(n2g + cb + 4);
            f32x4 b0 = *(const f32x4*)(n2b + cb), b1v = *(const f32x4*)(n2b + cb + 4);
            bf16x8 t;
#pragma unroll
            for (int e = 0; e < 4; e++) {
                t[e] = f2bf((xv[kk][0][e] - mu) * rstd * g0[e] + b0[e]);
                t[e + 4] = f2bf((xv[kk][1][e] - mu) * rstd * g1[e] + b1v[e]);
            }
            areg[mf][kk] = t;
        }
    }

    auto stage = [&](int jc, int buf) {
#pragma unroll
        for (int q = 0; q < 3; q++) {  // W1 chunk: 64x192
            int base = (wv * 3 + q) * 512;
            int E = base + lane * 8;
            int row = E / 192;
            int cb = (E - row * 192) >> 3;
            gload_lds16(W1g + (long)(jc * 64 + row) * 192 + ((cb ^ (row & 7)) << 3),
                        &Wbuf[buf][base]);
        }
#pragma unroll
        for (int q = 0; q < 3; q++) {  // W2 chunk: 192x64
            int base = (wv * 3 + q) * 512;
            int E = base + lane * 8;
            int row = E >> 6;
            int cb = (E & 63) >> 3;
            gload_lds16(W2g + (long)row * 768 + jc * 64 + ((cb ^ (row & 7)) << 3),
                        &Wbuf[buf][12288 + base]);
        }
    };

    stage(0, 0);
    __syncthreads();

    f32x4 acc[2][12] = {};

    for (int j = 0; j < 12; j++) {
        if (j < 11) stage(j + 1, (j + 1) & 1);
        const short* W1s = Wbuf[j & 1];
        const short* W2s = Wbuf[j & 1] + 12288;

        f32x4 hacc[4][2] = {};
#pragma unroll
        for (int kk = 0; kk < 6; kk++) {
            int cb = (kk << 2) + lg;
            bf16x8 wf[4];
#pragma unroll
            for (int hf = 0; hf < 4; hf++) {
                int r = (hf << 4) + lr;
                wf[hf] = *(const bf16x8*)(W1s + r * 192 + ((cb ^ (r & 7)) << 3));
            }
#pragma unroll
            for (int hf = 0; hf < 4; hf++)
#pragma unroll
                for (int mf = 0; mf < 2; mf++)
                    hacc[hf][mf] = __builtin_amdgcn_mfma_f32_16x16x32_bf16(
                        wf[hf], areg[mf][kk], hacc[hf][mf], 0, 0, 0);
        }

#pragma unroll
        for (int hf = 0; hf < 4; hf++) {
            f32x4 bv = *(const f32x4*)(b1 + j * 64 + (hf << 4) + (lg << 2));
#pragma unroll
            for (int mf = 0; mf < 2; mf++) {
                s16x4 hv;
#pragma unroll
                for (int e = 0; e < 4; e++) {
                    float v = hacc[hf][mf][e] + bv[e];
                    float inner = fmaf(-0.07135481627f, v * v, -1.595769122f);
                    float eterm = __expf(v * inner);  // exp(-2u)
                    float gl = v * __builtin_amdgcn_rcpf(1.f + eterm);
                    hv[e] = f2bf(gl);
                }
                int Mrow = (mf << 4) + lr;
                int blk = (hf << 1) | (lg >> 1);
                *(s16x4*)(hw + Mrow * 64 + ((blk ^ (Mrow & 7)) << 3) + ((lg & 1) << 2)) = hv;
            }
        }
        asm volatile("s_waitcnt lgkmcnt(0)" ::: "memory");

#pragma unroll
        for (int kk = 0; kk < 2; kk++) {
            int cb = (kk << 2) + lg;
            bf16x8 ah[2], bw[12];
#pragma unroll
            for (int mf = 0; mf < 2; mf++) {
                int r = (mf << 4) + lr;
                ah[mf] = *(const bf16x8*)(hw + r * 64 + ((cb ^ (r & 7)) << 3));
            }
#pragma unroll
            for (int nj = 0; nj < 12; nj++) {
                int r = (nj << 4) + lr;
                bw[nj] = *(const bf16x8*)(W2s + r * 64 + ((cb ^ (r & 7)) << 3));
            }
#pragma unroll
            for (int mf = 0; mf < 2; mf++)
#pragma unroll
                for (int nj = 0; nj < 12; nj++)
                    acc[mf][nj] = __builtin_amdgcn_mfma_f32_16x16x32_bf16(
                        ah[mf], bw[nj], acc[mf][nj], 0, 0, 0);
        }
        __syncthreads();
    }

#pragma unroll
    for (int mf = 0; mf < 2; mf++) {
        int rbase = m0 + (wv << 5) + (mf << 4) + (lg << 2);
#pragma unroll
        for (int nj = 0; nj < 12; nj++) {
            int col = (nj << 4) + lr;
            float bv = b2[col];
#pragma unroll
            for (int e = 0; e < 4; e++) {
                long r = rbase + e;
                resid[r * 192 + col] += acc[mf][nj][e] + bv;
            }
        }
    }
}

// ---------------- windowed attention: one wave per (window, head) ----------------
// PV uses swapped operands -> lane owns row n, d-cols in regs -> packed 8B stores.
__global__ __launch_bounds__(256) void attn_k(const short* __restrict__ qkv,
                                              const float* __restrict__ rpb,  // (343,6)
                                              short* __restrict__ o, int shifted) {
    __shared__ short lds[4 * 6144];
    const int wv = threadIdx.x >> 6, lane = threadIdx.x & 63;
    short* vT = lds + wv * 6144;
    short* P = lds + wv * 6144 + 2048;
    const int task = blockIdx.x * 4 + wv;
    const int win = task / 6, head = task - win * 6;
    const int lr = lane & 15, lg = lane >> 4;
    const long qbase = (long)win * 64 * 576 + head * 32;

    bf16x8 aq[4], bk[4];
#pragma unroll
    for (int bi = 0; bi < 4; bi++)
        aq[bi] = *(const bf16x8*)(qkv + qbase + (long)((bi << 4) + lr) * 576 + (lg << 3));
#pragma unroll
    for (int bj = 0; bj < 4; bj++)
        bk[bj] = *(const bf16x8*)(qkv + qbase + 192 + (long)((bj << 4) + lr) * 576 + (lg << 3));
    f32x4 s[4][4] = {};
#pragma unroll
    for (int bi = 0; bi < 4; bi++)
#pragma unroll
        for (int bj = 0; bj < 4; bj++)
            s[bi][bj] = __builtin_amdgcn_mfma_f32_16x16x32_bf16(aq[bi], bk[bj], s[bi][bj], 0, 0, 0);

#pragma unroll
    for (int j = 0; j < 4; j++) {
        bf16x8 vv = *(const bf16x8*)(qkv + qbase + 384 + (long)lane * 576 + (j << 3));
#pragma unroll
        for (int e = 0; e < 8; e++) {
            int d = (j << 3) + e;
            vT[d * 64 + (((lane >> 3) ^ (d & 7)) << 3) + (lane & 7)] = vv[e];
        }
    }

    const float SCALE = 0.17677669529663687f;
    int widx = win & 511;
    int wh = widx >> 6, ww = (widx >> 3) & 7, wt = widx & 7;
    int ihm[4], iwm[4], itm[4], lblm[4];
#pragma unroll
    for (int bj = 0; bj < 4; bj++) {
        int m = (bj << 4) + lr;
        ihm[bj] = m >> 4; iwm[bj] = (m >> 2) & 3; itm[bj] = m & 3;
        lblm[bj] = reg3((wh << 2) + ihm[bj]) * 9 + reg3((ww << 2) + iwm[bj]) * 3 + reg3((wt << 2) + itm[bj]);
    }
#pragma unroll
    for (int bi = 0; bi < 4; bi++) {
#pragma unroll
        for (int e = 0; e < 4; e++) {
            int n = (bi << 4) + (lg << 2) + e;
            int ihn = n >> 4, iwn = (n >> 2) & 3, itn = n & 3;
            int lbln = reg3((wh << 2) + ihn) * 9 + reg3((ww << 2) + iwn) * 3 + reg3((wt << 2) + itn);
#pragma unroll
            for (int bj = 0; bj < 4; bj++) {
                int idx = (ihn - ihm[bj] + 3) * 49 + (iwn - iwm[bj] + 3) * 7 + (itn - itm[bj] + 3);
                float bias = rpb[idx * 6 + head];
                float val = s[bi][bj][e] * SCALE + bias;
                if (shifted && lbln != lblm[bj]) val -= 100.f;
                s[bi][bj][e] = val;
            }
        }
    }

#pragma unroll
    for (int bi = 0; bi < 4; bi++) {
#pragma unroll
        for (int e = 0; e < 4; e++) {
            float mx = s[bi][0][e];
#pragma unroll
            for (int bj = 1; bj < 4; bj++) mx = fmaxf(mx, s[bi][bj][e]);
#pragma unroll
            for (int off = 1; off < 16; off <<= 1) mx = fmaxf(mx, __shfl_xor(mx, off, 64));
            float sm = 0.f;
#pragma unroll
            for (int bj = 0; bj < 4; bj++) {
                float p = __expf(s[bi][bj][e] - mx);
                s[bi][bj][e] = p;
                sm += p;
            }
#pragma unroll
            for (int off = 1; off < 16; off <<= 1) sm += __shfl_xor(sm, off, 64);
            float rinv = 1.f / sm;
            int n = (bi << 4) + (lg << 2) + e;
#pragma unroll
            for (int bj = 0; bj < 4; bj++) {
                int m = (bj << 4) + lr;
                P[n * 64 + (((m >> 3) ^ (n & 7)) << 3) + (m & 7)] = f2bf(s[bi][bj][e] * rinv);
            }
        }
    }

    // O = P @ V with swapped operands: oacc = mfma(vT_frag, P_frag)
    f32x4 oacc[4][2] = {};
#pragma unroll
    for (int ks = 0; ks < 2; ks++) {
        bf16x8 ap[4], bv2[2];
        int kb = (ks << 2) + lg;
#pragma unroll
        for (int bi = 0; bi < 4; bi++) {
            int r = (bi << 4) + lr;
            ap[bi] = *(const bf16x8*)(P + r * 64 + ((kb ^ (r & 7)) << 3));
        }
#pragma unroll
        for (int nf = 0; nf < 2; nf++) {
            int d = (nf << 4) + lr;
            bv2[nf] = *(const bf16x8*)(vT + d * 64 + ((kb ^ (d & 7)) << 3));
        }
#pragma unroll
        for (int bi = 0; bi < 4; bi++)
#pragma unroll
            for (int nf = 0; nf < 2; nf++)
                oacc[bi][nf] = __builtin_amdgcn_mfma_f32_16x16x32_bf16(bv2[nf], ap[bi], oacc[bi][nf], 0, 0, 0);
    }
    // packed 8B stores: lane owns row n=(bi<<4)+lr, cols d=(nf<<4)+(lg<<2)..+3
#pragma unroll
    for (int bi = 0; bi < 4; bi++) {
        long nbase = ((long)win * 64 + (bi << 4) + lr) * 192 + head * 32;
#pragma unroll
        for (int nf = 0; nf < 2; nf++) {
            int d0 = (nf << 4) + (lg << 2);
            s16x4 pk;
#pragma unroll
            for (int e = 0; e < 4; e++) pk[e] = f2bf(oacc[bi][nf][e]);
            *(s16x4*)(o + nbase + d0) = pk;
        }
    }
}

// ---------------- depthwise 3x3x3 conv, register-blocked along t ----------------
__global__ __launch_bounds__(192) void dw_k(const float* __restrict__ xf,
                                            const float* __restrict__ w,
                                            const float* __restrict__ db,
                                            short* __restrict__ out) {
    int c = threadIdx.x;
    int blk = blockIdx.x;
    int t0 = (blk & 3) << 3;
    int bhw = blk >> 2;
    int b = bhw >> 10, h = (bhw >> 5) & 31, wq = bhw & 31;

    float wr[27];
#pragma unroll
    for (int k = 0; k < 27; k++) wr[k] = w[c * 27 + k];
    float bias = db[c];
    float acc[8];
#pragma unroll
    for (int j = 0; j < 8; j++) acc[j] = bias;

#pragma unroll
    for (int a = 0; a < 3; a++) {
        int hh = h + a - 1;
        if (hh < 0 || hh > 31) continue;
#pragma unroll
        for (int bb = 0; bb < 3; bb++) {
            int ww = wq + bb - 1;
            if (ww < 0 || ww > 31) continue;
            const float* base = xf + ((long)(b << 15) + (hh << 10) + (ww << 5)) * 192 + c;
            float val[10];
#pragma unroll
            for (int tt = 0; tt < 10; tt++) {
                int t = t0 + tt - 1;
                val[tt] = (t >= 0 && t < 32) ? base[t * 192] : 0.f;
            }
#pragma unroll
            for (int d = 0; d < 3; d++) {
                float wv = wr[a * 9 + bb * 3 + d];
#pragma unroll
                for (int j = 0; j < 8; j++)
                    acc[j] = fmaf(val[j + d], wv, acc[j]);
            }
        }
    }
    long obase = ((long)(b << 15) + (h << 10) + (wq << 5) + t0) * 192 + c;
#pragma unroll
    for (int j = 0; j < 8; j++) out[obase + j * 192] = f2bf(acc[j]);
}

// ---------------- launch ----------------
extern "C" void kernel_launch(void* const* d_in, const int* in_sizes, int n_in,
                              void* d_out, int out_size, void* d_ws, size_t ws_size,
                              hipStream_t stream) {
    const float* x      = (const float*)d_in[0];
    const float* n1g    = (const float*)d_in[1];
    const float* n1b    = (const float*)d_in[2];
    const float* qkv_w  = (const float*)d_in[3];
    const float* qkv_b  = (const float*)d_in[4];
    const float* rpb    = (const float*)d_in[5];
    const float* proj_w = (const float*)d_in[6];
    const float* proj_b = (const float*)d_in[7];
    const float* n2g    = (const float*)d_in[8];
    const float* n2b    = (const float*)d_in[9];
    const float* fc1_w  = (const float*)d_in[10];
    const float* fc1_b  = (const float*)d_in[11];
    const float* fc2_w  = (const float*)d_in[12];
    const float* fc2_b  = (const float*)d_in[13];
    const float* dw_w   = (const float*)d_in[14];
    const float* dw_b   = (const float*)d_in[15];
    const float* pw_w   = (const float*)d_in[16];
    const float* pw_b   = (const float*)d_in[17];
    const float* bn_g   = (const float*)d_in[18];
    const float* bn_b   = (const float*)d_in[19];
    float* outF = (float*)d_out;

    char* ws = (char*)d_ws;
    float* XF = (float*)ws;
    short* Abuf = (short*)(ws + 50331648);
    short* Bbuf = (short*)(ws + 150994944);
    short* WT = (short*)(ws + 226492416);

    transpose_in<<<dim3(1024, 6, 2), dim3(32, 8), 0, stream>>>(x, XF);
    prep_w<<<7056, 256, 0, stream>>>(qkv_w, proj_w, fc1_w, fc2_w, pw_w, WT);

    for (int i = 0; i < 4; i++) {
        int shifted = i & 1;
        int shift = shifted ? 2 : 0;
        qkv_k<<<512, 256, 0, stream>>>(XF, WT + (long)i * 442368, qkv_b + i * 576,
                                       n1g + i * 192, n1b + i * 192, Bbuf, shift);
        attn_k<<<1536, 256, 0, stream>>>(Bbuf, rpb + i * 2058, Abuf, shifted);
        wk_k<3><<<512, 256, 0, stream>>>(Abuf, WT + (long)i * 442368 + 110592, proj_b + i * 192,
                                         XF, nullptr, nullptr, nullptr, shift);
        mlp_k<<<256, 512, 0, stream>>>(XF, WT + (long)i * 442368 + 147456,
                                       WT + (long)i * 442368 + 294912,
                                       fc1_b + i * 768, fc2_b + i * 192,
                                       n2g + i * 192, n2b + i * 192, XF);
    }

    dw_k<<<8192, 192, 0, stream>>>(XF, dw_w, dw_b, Abuf);
    wk_k<4><<<512, 256, 0, stream>>>(Abuf, WT + 1769472, pw_b,
                                     nullptr, outF, bn_g, bn_b, 0);
}

// Round 15
// 761.791 us; speedup vs baseline: 1.1055x; 1.0063x over previous
//
#include <hip/hip_runtime.h>
#include <hip/hip_bf16.h>

// ---------------- constants ----------------
// C=192, H=W=T=32, WS=4, SS=2, NH=6, HD=32, N=64 tokens/window
// L = 32768 tokens/batch, B=2 -> M = 65536 rows everywhere.
#define DI __device__ __forceinline__

typedef short bf16x8 __attribute__((ext_vector_type(8)));
typedef float f32x4 __attribute__((ext_vector_type(4)));
typedef short s16x4 __attribute__((ext_vector_type(4)));

DI short f2bf(float f) {
    __hip_bfloat16 h = __float2bfloat16(f);
    return *reinterpret_cast<short*>(&h);
}

DI void gload_lds16(const short* gsrc, short* ldst) {
    __builtin_amdgcn_global_load_lds(
        (const __attribute__((address_space(1))) void*)gsrc,
        (__attribute__((address_space(3))) void*)ldst, 16, 0, 0);
}

// region label along one axis for the shift mask: [0,28)->0, [28,30)->1, [30,32)->2
DI int reg3(int p) { return p < 28 ? 0 : (p < 30 ? 1 : 2); }

// ---------------- input transpose: x (B,C,L) -> xf (B,L,C) f32 ----------------
__global__ __launch_bounds__(256) void transpose_in(const float* __restrict__ x,
                                                    float* __restrict__ xf) {
    __shared__ float tile[32][33];
    int b = blockIdx.z;
    int c0 = blockIdx.y * 32;
    int l0 = blockIdx.x * 32;
    int tx = threadIdx.x, ty = threadIdx.y;  // 32 x 8
#pragma unroll
    for (int i = 0; i < 32; i += 8)
        tile[ty + i][tx] = x[(long)(b * 192 + c0 + ty + i) * 32768 + l0 + tx];
    __syncthreads();
#pragma unroll
    for (int i = 0; i < 32; i += 8)
        xf[(long)(b * 32768 + l0 + ty + i) * 192 + c0 + tx] = tile[tx][ty + i];
}

// ---------------- weight prep ----------------
__global__ __launch_bounds__(256) void prep_w(const float* __restrict__ qkv_w,
                                              const float* __restrict__ proj_w,
                                              const float* __restrict__ fc1_w,
                                              const float* __restrict__ fc2_w,
                                              const float* __restrict__ pw_w,
                                              short* __restrict__ wt) {
    int i = blockIdx.x * 256 + threadIdx.x;
    float v;
    if (i < 1769472) {
        int b4 = i / 442368, r = i - b4 * 442368;
        if (r < 110592) { int n = r / 192, k = r - n * 192; v = qkv_w[b4 * 110592 + k * 576 + n]; }
        else if (r < 147456) { int r2 = r - 110592; int n = r2 / 192, k = r2 - n * 192; v = proj_w[b4 * 36864 + k * 192 + n]; }
        else if (r < 294912) { int r2 = r - 147456; int n = r2 / 192, k = r2 - n * 192; v = fc1_w[b4 * 147456 + k * 768 + n]; }
        else { int r2 = r - 294912; int n = r2 / 768, k = r2 - n * 768; v = fc2_w[b4 * 147456 + k * 192 + n]; }
        wt[i] = f2bf(v);
    } else {
        int r = i - 1769472;
        wt[i] = f2bf(pw_w[r]);
    }
}

// ---------------- fused LN1 + QKV (round-8 proven form) ----------------
__global__ __launch_bounds__(256) void qkv_k(const float* __restrict__ XF,
                                             const short* __restrict__ Wg,  // qkvT (576,192)
                                             const float* __restrict__ bias,
                                             const float* __restrict__ n1g,
                                             const float* __restrict__ n1b,
                                             short* __restrict__ out, int shift) {
    __shared__ short Ws[2][12288];
    const int tid = threadIdx.x;
    const int wv = tid >> 6, lane = tid & 63;
    const int lr = lane & 15, lg = lane >> 4;
    const int mt = ((blockIdx.x & 7) << 6) + (blockIdx.x >> 3);  // XCD swizzle, 512 blocks
    const int m0 = mt << 7;

    // ---- LN1 prologue with roll+window-partition gather ----
    bf16x8 areg[2][6];
#pragma unroll
    for (int mf = 0; mf < 2; mf++) {
        int row = m0 + (wv << 5) + (mf << 4) + lr;
        int b = row >> 15, r = row & 32767, widx = r >> 6, n = r & 63;
        int wh = widx >> 6, ww = (widx >> 3) & 7, wt = widx & 7;
        int ih = n >> 4, iw = (n >> 2) & 3, it = n & 3;
        int h = ((wh << 2) + ih + shift) & 31;
        int w = ((ww << 2) + iw + shift) & 31;
        int t = ((wt << 2) + it + shift) & 31;
        const float* rp = XF + ((long)(b << 15) + (h << 10) + (w << 5) + t) * 192;
        f32x4 xv[6][2];
        float s = 0.f, sq = 0.f;
#pragma unroll
        for (int kk = 0; kk < 6; kk++)
#pragma unroll
            for (int q = 0; q < 2; q++) {
                xv[kk][q] = *(const f32x4*)(rp + kk * 32 + (lg << 3) + q * 4);
#pragma unroll
                for (int e = 0; e < 4; e++) {
                    s += xv[kk][q][e];
                    sq += xv[kk][q][e] * xv[kk][q][e];
                }
            }
        s += __shfl_xor(s, 16, 64); s += __shfl_xor(s, 32, 64);
        sq += __shfl_xor(sq, 16, 64); sq += __shfl_xor(sq, 32, 64);
        float mu = s * (1.f / 192.f);
        float var = sq * (1.f / 192.f) - mu * mu;
        float rstd = rsqrtf(var + 1e-5f);
#pragma unroll
        for (int kk = 0; kk < 6; kk++) {
            int cb = kk * 32 + (lg << 3);
            f32x4 g0 = *(const f32x4*)(n1g + cb), g1 = *(const f32x4*)(n1g + cb + 4);
            f32x4 b0 = *(const f32x4*)(n1b + cb), b1v = *(const f32x4*)(n1b + cb + 4);
            bf16x8 tt;
#pragma unroll
            for (int e = 0; e < 4; e++) {
                tt[e] = f2bf((xv[kk][0][e] - mu) * rstd * g0[e] + b0[e]);
                tt[e + 4] = f2bf((xv[kk][1][e] - mu) * rstd * g1[e] + b1v[e]);
            }
            areg[mf][kk] = tt;
        }
    }

    auto stage = [&](int jc, int buf) {
#pragma unroll
        for (int q = 0; q < 6; q++) {
            int base = (wv * 6 + q) * 512;
            int E = base + lane * 8;
            int row = E / 192;
            int cb = (E - row * 192) >> 3;
            gload_lds16(Wg + (long)(jc * 64 + row) * 192 + ((cb ^ (row & 7)) << 3),
                        &Ws[buf][base]);
        }
    };

    stage(0, 0);
    __syncthreads();

    for (int j = 0; j < 9; j++) {
        if (j < 8) stage(j + 1, (j + 1) & 1);
        const short* W = Ws[j & 1];
        f32x4 acc[2][4] = {};
#pragma unroll
        for (int kk = 0; kk < 6; kk++) {
            int cb = (kk << 2) + lg;
            bf16x8 wf[4];
#pragma unroll
            for (int nf = 0; nf < 4; nf++) {
                int r = (nf << 4) + lr;
                wf[nf] = *(const bf16x8*)(W + r * 192 + ((cb ^ (r & 7)) << 3));
            }
#pragma unroll
            for (int mf = 0; mf < 2; mf++)
#pragma unroll
                for (int nf = 0; nf < 4; nf++)
                    acc[mf][nf] = __builtin_amdgcn_mfma_f32_16x16x32_bf16(
                        areg[mf][kk], wf[nf], acc[mf][nf], 0, 0, 0);
        }
#pragma unroll
        for (int mf = 0; mf < 2; mf++) {
#pragma unroll
            for (int nf = 0; nf < 4; nf++) {
                int col = j * 64 + (nf << 4) + lr;
                float bv = bias[col];
#pragma unroll
                for (int e = 0; e < 4; e++) {
                    int row = m0 + (wv << 5) + (mf << 4) + (lg << 2) + e;
                    out[(long)row * 576 + col] = f2bf(acc[mf][nf][e] + bv);
                }
            }
        }
        __syncthreads();
    }
}

// ---------------- A-in-regs GEMM with full W in LDS (round-8 proven form) ----------------
// MODE 3: proj -> window-reverse+roll, resid += v
// MODE 4: pointwise conv -> BN + ReLU, f32 channel-major out
template <int MODE>
__global__ __launch_bounds__(256) void wk_k(const short* __restrict__ A,
                                            const short* __restrict__ Wg,  // (192,192)
                                            const float* __restrict__ bias,
                                            float* __restrict__ resid, float* __restrict__ outF,
                                            const float* __restrict__ bng,
                                            const float* __restrict__ bnb, int shift) {
    __shared__ short Ws[36864];
    const int tid = threadIdx.x;
    const int wv = tid >> 6, lane = tid & 63;
    const int lr = lane & 15, lg = lane >> 4;
    const int mt = ((blockIdx.x & 7) << 6) + (blockIdx.x >> 3);  // 512 blocks
    const int m0 = mt << 7;

    bf16x8 areg[2][6];
#pragma unroll
    for (int mf = 0; mf < 2; mf++)
#pragma unroll
        for (int kk = 0; kk < 6; kk++)
            areg[mf][kk] = *(const bf16x8*)(A + (long)(m0 + (wv << 5) + (mf << 4) + lr) * 192 + kk * 32 + (lg << 3));

#pragma unroll
    for (int q = 0; q < 18; q++) {
        int base = (wv * 18 + q) * 512;
        int E = base + lane * 8;
        int row = E / 192;
        int cb = (E - row * 192) >> 3;
        gload_lds16(Wg + (long)row * 192 + ((cb ^ (row & 7)) << 3), Ws + base);
    }
    __syncthreads();

    f32x4 acc[2][12] = {};
#pragma unroll
    for (int kk = 0; kk < 6; kk++) {
        int cb = (kk << 2) + lg;
#pragma unroll
        for (int njb = 0; njb < 3; njb++) {
            bf16x8 wf[4];
#pragma unroll
            for (int q = 0; q < 4; q++) {
                int r = ((njb * 4 + q) << 4) + lr;
                wf[q] = *(const bf16x8*)(Ws + r * 192 + ((cb ^ (r & 7)) << 3));
            }
#pragma unroll
            for (int mf = 0; mf < 2; mf++)
#pragma unroll
                for (int q = 0; q < 4; q++)
                    acc[mf][njb * 4 + q] = __builtin_amdgcn_mfma_f32_16x16x32_bf16(
                        areg[mf][kk], wf[q], acc[mf][njb * 4 + q], 0, 0, 0);
        }
    }

#pragma unroll
    for (int mf = 0; mf < 2; mf++) {
        int rbase = m0 + (wv << 5) + (mf << 4) + (lg << 2);
#pragma unroll
        for (int nj = 0; nj < 12; nj++) {
            int col = (nj << 4) + lr;
            float bv = bias[col];
            if (MODE == 4) {
                float sc = 0.9999950000374997f * bng[col];
                float bb = bnb[col];
                f32x4 o;
#pragma unroll
                for (int e = 0; e < 4; e++) {
                    float v = (acc[mf][nj][e] + bv) * sc + bb;
                    o[e] = v > 0.f ? v : 0.f;
                }
                int b = rbase >> 15, l = rbase & 32767;
                *(f32x4*)(outF + ((long)(b * 192 + col) << 15) + l) = o;
            } else {  // MODE 3
#pragma unroll
                for (int e = 0; e < 4; e++) {
                    int r = rbase + e;
                    int b = r >> 15, rr = r & 32767, widx = rr >> 6, n = rr & 63;
                    int wh = widx >> 6, ww = (widx >> 3) & 7, wt = widx & 7;
                    int ih = n >> 4, iw = (n >> 2) & 3, it = n & 3;
                    int h = ((wh << 2) + ih + shift) & 31;
                    int w = ((ww << 2) + iw + shift) & 31;
                    int t = ((wt << 2) + it + shift) & 31;
                    long tok = (long)(b << 15) + (h << 10) + (w << 5) + t;
                    resid[tok * 192 + col] += acc[mf][nj][e] + bv;
                }
            }
        }
    }
}

// ---------------- fused LN2+MLP v8: pair-split (halved per-wave W LDS reads) ----------------
// Block = 128 rows, 8 waves. Wave pair (2p, 2p+1) shares 32 rows; role 0 computes
// hidden 0-31 / N-cols 0-95, role 1 the other halves. Hs is pair-shared (block
// barrier after GELU). Per-wave W reads halve vs v5. LDS = 96KB Wdbuf + 16KB Hs.
__global__ __launch_bounds__(512, 2) void mlp_k(const float* __restrict__ XF,
                                                const short* __restrict__ W1g,  // fc1T (768,192)
                                                const short* __restrict__ W2g,  // fc2T (192,768)
                                                const float* __restrict__ b1,
                                                const float* __restrict__ b2,
                                                const float* __restrict__ n2g,
                                                const float* __restrict__ n2b,
                                                float* __restrict__ resid) {
    __shared__ short Wbuf[2][24576];  // per buf: W1 64x192 @0, W2 192x64 @12288
    __shared__ short Hs[4][2048];     // per pair: 32x64 (XOR-swizzled)
    const int tid = threadIdx.x;
    const int wv = tid >> 6, lane = tid & 63;
    const int lr = lane & 15, lg = lane >> 4;
    const int pair = wv >> 1, role = wv & 1;
    const int mt = ((blockIdx.x & 7) << 6) + (blockIdx.x >> 3);  // XCD swizzle, 512 blocks
    const int m0 = mt << 7;
    short* hw = &Hs[pair][0];

    // ---- LN2 prologue: pair-shared 32 rows -> normalized bf16 fragments ----
    bf16x8 areg[2][6];
#pragma unroll
    for (int mf = 0; mf < 2; mf++) {
        const float* rp = XF + (long)(m0 + (pair << 5) + (mf << 4) + lr) * 192;
        f32x4 xv[6][2];
        float s = 0.f, sq = 0.f;
#pragma unroll
        for (int kk = 0; kk < 6; kk++)
#pragma unroll
            for (int q = 0; q < 2; q++) {
                xv[kk][q] = *(const f32x4*)(rp + kk * 32 + (lg << 3) + q * 4);
#pragma unroll
                for (int e = 0; e < 4; e++) {
                    s += xv[kk][q][e];
                    sq += xv[kk][q][e] * xv[kk][q][e];
                }
            }
        s += __shfl_xor(s, 16, 64); s += __shfl_xor(s, 32, 64);
        sq += __shfl_xor(sq, 16, 64); sq += __shfl_xor(sq, 32, 64);
        float mu = s * (1.f / 192.f);
        float var = sq * (1.f / 192.f) - mu * mu;
        float rstd = rsqrtf(var + 1e-5f);
#pragma unroll
        for (int kk = 0; kk < 6; kk++) {
            int cb = kk * 32 + (lg << 3);
            f32x4 g0 = *(const f32x4*)(n2g + cb), g1 = *(const f32x4*)(n2g + cb + 4);
            f32x4 b0 = *(const f32x4*)(n2b + cb), b1v = *(const f32x4*)(n2b + cb + 4);
            bf16x8 t;
#pragma unroll
            for (int e = 0; e < 4; e++) {
                t[e] = f2bf((xv[kk][0][e] - mu) * rstd * g0[e] + b0[e]);
                t[e + 4] = f2bf((xv[kk][1][e] - mu) * rstd * g1[e] + b1v[e]);
            }
            areg[mf][kk] = t;
        }
    }

    auto stage = [&](int jc, int buf) {
#pragma unroll
        for (int q = 0; q < 3; q++) {  // W1 chunk: 64x192
            int base = (wv * 3 + q) * 512;
            int E = base + lane * 8;
            int row = E / 192;
            int cb = (E - row * 192) >> 3;
            gload_lds16(W1g + (long)(jc * 64 + row) * 192 + ((cb ^ (row & 7)) << 3),
                        &Wbuf[buf][base]);
        }
#pragma unroll
        for (int q = 0; q < 3; q++) {  // W2 chunk: 192x64
            int base = (wv * 3 + q) * 512;
            int E = base + lane * 8;
            int row = E >> 6;
            int cb = (E & 63) >> 3;
            gload_lds16(W2g + (long)row * 768 + jc * 64 + ((cb ^ (row & 7)) << 3),
                        &Wbuf[buf][12288 + base]);
        }
    };

    stage(0, 0);
    __syncthreads();

    f32x4 acc[2][6] = {};

    for (int j = 0; j < 12; j++) {
        if (j < 11) stage(j + 1, (j + 1) & 1);
        const short* W1s = Wbuf[j & 1];
        const short* W2s = Wbuf[j & 1] + 12288;

        // ---- GEMM1 (role's hidden half): hacc[q][mf], hf = role*2+q ----
        f32x4 hacc[2][2] = {};
#pragma unroll
        for (int kk = 0; kk < 6; kk++) {
            int cb = (kk << 2) + lg;
            bf16x8 wf[2];
#pragma unroll
            for (int q = 0; q < 2; q++) {
                int r = (((role << 1) + q) << 4) + lr;
                wf[q] = *(const bf16x8*)(W1s + r * 192 + ((cb ^ (r & 7)) << 3));
            }
#pragma unroll
            for (int q = 0; q < 2; q++)
#pragma unroll
                for (int mf = 0; mf < 2; mf++)
                    hacc[q][mf] = __builtin_amdgcn_mfma_f32_16x16x32_bf16(
                        wf[q], areg[mf][kk], hacc[q][mf], 0, 0, 0);
        }

        // ---- GELU(+b1) -> pair-shared Hs ----
#pragma unroll
        for (int q = 0; q < 2; q++) {
            int hf = (role << 1) + q;
            f32x4 bv = *(const f32x4*)(b1 + j * 64 + (hf << 4) + (lg << 2));
#pragma unroll
            for (int mf = 0; mf < 2; mf++) {
                s16x4 hv;
#pragma unroll
                for (int e = 0; e < 4; e++) {
                    float v = hacc[q][mf][e] + bv[e];
                    float inner = fmaf(-0.07135481627f, v * v, -1.595769122f);
                    float eterm = __expf(v * inner);  // exp(-2u)
                    float gl = v * __builtin_amdgcn_rcpf(1.f + eterm);
                    hv[e] = f2bf(gl);
                }
                int Mrow = (mf << 4) + lr;
                int blk = (hf << 1) | (lg >> 1);
                *(s16x4*)(hw + Mrow * 64 + ((blk ^ (Mrow & 7)) << 3) + ((lg & 1) << 2)) = hv;
            }
        }
        __syncthreads();  // pair h-halves visible

        // ---- GEMM2: acc += h @ W2 (role's N-cols: nj = role*6 + 0..5) ----
#pragma unroll
        for (int kk = 0; kk < 2; kk++) {
            int cb = (kk << 2) + lg;
            bf16x8 ah[2], bw[6];
#pragma unroll
            for (int mf = 0; mf < 2; mf++) {
                int r = (mf << 4) + lr;
                ah[mf] = *(const bf16x8*)(hw + r * 64 + ((cb ^ (r & 7)) << 3));
            }
#pragma unroll
            for (int nq = 0; nq < 6; nq++) {
                int r = ((role * 6 + nq) << 4) + lr;
                bw[nq] = *(const bf16x8*)(W2s + r * 64 + ((cb ^ (r & 7)) << 3));
            }
#pragma unroll
            for (int mf = 0; mf < 2; mf++)
#pragma unroll
                for (int nq = 0; nq < 6; nq++)
                    acc[mf][nq] = __builtin_amdgcn_mfma_f32_16x16x32_bf16(
                        ah[mf], bw[nq], acc[mf][nq], 0, 0, 0);
        }
        __syncthreads();  // Wbuf consumed; vmcnt drained -> next buf ready
    }

    // ---- epilogue: resid += acc + b2 (role's 96 cols) ----
#pragma unroll
    for (int mf = 0; mf < 2; mf++) {
        int rbase = m0 + (pair << 5) + (mf << 4) + (lg << 2);
#pragma unroll
        for (int nq = 0; nq < 6; nq++) {
            int col = ((role * 6 + nq) << 4) + lr;
            float bv = b2[col];
#pragma unroll
            for (int e = 0; e < 4; e++) {
                long r = rbase + e;
                resid[r * 192 + col] += acc[mf][nq][e] + bv;
            }
        }
    }
}

// ---------------- windowed attention (round-8 proven form) ----------------
__global__ __launch_bounds__(256) void attn_k(const short* __restrict__ qkv,
                                              const float* __restrict__ rpb,  // (343,6)
                                              short* __restrict__ o, int shifted) {
    __shared__ short lds[4 * 6144];
    const int wv = threadIdx.x >> 6, lane = threadIdx.x & 63;
    short* vT = lds + wv * 6144;
    short* P = lds + wv * 6144 + 2048;
    const int task = blockIdx.x * 4 + wv;
    const int win = task / 6, head = task - win * 6;
    const int lr = lane & 15, lg = lane >> 4;
    const long qbase = (long)win * 64 * 576 + head * 32;

    bf16x8 aq[4], bk[4];
#pragma unroll
    for (int bi = 0; bi < 4; bi++)
        aq[bi] = *(const bf16x8*)(qkv + qbase + (long)((bi << 4) + lr) * 576 + (lg << 3));
#pragma unroll
    for (int bj = 0; bj < 4; bj++)
        bk[bj] = *(const bf16x8*)(qkv + qbase + 192 + (long)((bj << 4) + lr) * 576 + (lg << 3));
    f32x4 s[4][4] = {};
#pragma unroll
    for (int bi = 0; bi < 4; bi++)
#pragma unroll
        for (int bj = 0; bj < 4; bj++)
            s[bi][bj] = __builtin_amdgcn_mfma_f32_16x16x32_bf16(aq[bi], bk[bj], s[bi][bj], 0, 0, 0);

#pragma unroll
    for (int j = 0; j < 4; j++) {
        bf16x8 vv = *(const bf16x8*)(qkv + qbase + 384 + (long)lane * 576 + (j << 3));
#pragma unroll
        for (int e = 0; e < 8; e++) {
            int d = (j << 3) + e;
            vT[d * 64 + (((lane >> 3) ^ (d & 7)) << 3) + (lane & 7)] = vv[e];
        }
    }

    const float SCALE = 0.17677669529663687f;
    int widx = win & 511;
    int wh = widx >> 6, ww = (widx >> 3) & 7, wt = widx & 7;
    int ihm[4], iwm[4], itm[4], lblm[4];
#pragma unroll
    for (int bj = 0; bj < 4; bj++) {
        int m = (bj << 4) + lr;
        ihm[bj] = m >> 4; iwm[bj] = (m >> 2) & 3; itm[bj] = m & 3;
        lblm[bj] = reg3((wh << 2) + ihm[bj]) * 9 + reg3((ww << 2) + iwm[bj]) * 3 + reg3((wt << 2) + itm[bj]);
    }
#pragma unroll
    for (int bi = 0; bi < 4; bi++) {
#pragma unroll
        for (int e = 0; e < 4; e++) {
            int n = (bi << 4) + (lg << 2) + e;
            int ihn = n >> 4, iwn = (n >> 2) & 3, itn = n & 3;
            int lbln = reg3((wh << 2) + ihn) * 9 + reg3((ww << 2) + iwn) * 3 + reg3((wt << 2) + itn);
#pragma unroll
            for (int bj = 0; bj < 4; bj++) {
                int idx = (ihn - ihm[bj] + 3) * 49 + (iwn - iwm[bj] + 3) * 7 + (itn - itm[bj] + 3);
                float bias = rpb[idx * 6 + head];
                float val = s[bi][bj][e] * SCALE + bias;
                if (shifted && lbln != lblm[bj]) val -= 100.f;
                s[bi][bj][e] = val;
            }
        }
    }

#pragma unroll
    for (int bi = 0; bi < 4; bi++) {
#pragma unroll
        for (int e = 0; e < 4; e++) {
            float mx = s[bi][0][e];
#pragma unroll
            for (int bj = 1; bj < 4; bj++) mx = fmaxf(mx, s[bi][bj][e]);
#pragma unroll
            for (int off = 1; off < 16; off <<= 1) mx = fmaxf(mx, __shfl_xor(mx, off, 64));
            float sm = 0.f;
#pragma unroll
            for (int bj = 0; bj < 4; bj++) {
                float p = __expf(s[bi][bj][e] - mx);
                s[bi][bj][e] = p;
                sm += p;
            }
#pragma unroll
            for (int off = 1; off < 16; off <<= 1) sm += __shfl_xor(sm, off, 64);
            float rinv = 1.f / sm;
            int n = (bi << 4) + (lg << 2) + e;
#pragma unroll
            for (int bj = 0; bj < 4; bj++) {
                int m = (bj << 4) + lr;
                P[n * 64 + (((m >> 3) ^ (n & 7)) << 3) + (m & 7)] = f2bf(s[bi][bj][e] * rinv);
            }
        }
    }

    f32x4 oacc[4][2] = {};
#pragma unroll
    for (int ks = 0; ks < 2; ks++) {
        bf16x8 ap[4], bv2[2];
        int kb = (ks << 2) + lg;
#pragma unroll
        for (int bi = 0; bi < 4; bi++) {
            int r = (bi << 4) + lr;
            ap[bi] = *(const bf16x8*)(P + r * 64 + ((kb ^ (r & 7)) << 3));
        }
#pragma unroll
        for (int nf = 0; nf < 2; nf++) {
            int d = (nf << 4) + lr;
            bv2[nf] = *(const bf16x8*)(vT + d * 64 + ((kb ^ (d & 7)) << 3));
        }
#pragma unroll
        for (int bi = 0; bi < 4; bi++)
#pragma unroll
            for (int nf = 0; nf < 2; nf++)
                oacc[bi][nf] = __builtin_amdgcn_mfma_f32_16x16x32_bf16(ap[bi], bv2[nf], oacc[bi][nf], 0, 0, 0);
    }
#pragma unroll
    for (int bi = 0; bi < 4; bi++)
#pragma unroll
        for (int nf = 0; nf < 2; nf++)
#pragma unroll
            for (int e = 0; e < 4; e++) {
                int n = (bi << 4) + (lg << 2) + e;
                int d = (nf << 4) + lr;
                o[((long)win * 64 + n) * 192 + head * 32 + d] = f2bf(oacc[bi][nf][e]);
            }
}

// ---------------- depthwise 3x3x3 conv, register-blocked along t ----------------
__global__ __launch_bounds__(192) void dw_k(const float* __restrict__ xf,
                                            const float* __restrict__ w,
                                            const float* __restrict__ db,
                                            short* __restrict__ out) {
    int c = threadIdx.x;
    int blk = blockIdx.x;
    int t0 = (blk & 3) << 3;
    int bhw = blk >> 2;
    int b = bhw >> 10, h = (bhw >> 5) & 31, wq = bhw & 31;

    float wr[27];
#pragma unroll
    for (int k = 0; k < 27; k++) wr[k] = w[c * 27 + k];
    float bias = db[c];
    float acc[8];
#pragma unroll
    for (int j = 0; j < 8; j++) acc[j] = bias;

#pragma unroll
    for (int a = 0; a < 3; a++) {
        int hh = h + a - 1;
        if (hh < 0 || hh > 31) continue;
#pragma unroll
        for (int bb = 0; bb < 3; bb++) {
            int ww = wq + bb - 1;
            if (ww < 0 || ww > 31) continue;
            const float* base = xf + ((long)(b << 15) + (hh << 10) + (ww << 5)) * 192 + c;
            float val[10];
#pragma unroll
            for (int tt = 0; tt < 10; tt++) {
                int t = t0 + tt - 1;
                val[tt] = (t >= 0 && t < 32) ? base[t * 192] : 0.f;
            }
#pragma unroll
            for (int d = 0; d < 3; d++) {
                float wv = wr[a * 9 + bb * 3 + d];
#pragma unroll
                for (int j = 0; j < 8; j++)
                    acc[j] = fmaf(val[j + d], wv, acc[j]);
            }
        }
    }
    long obase = ((long)(b << 15) + (h << 10) + (wq << 5) + t0) * 192 + c;
#pragma unroll
    for (int j = 0; j < 8; j++) out[obase + j * 192] = f2bf(acc[j]);
}

// ---------------- launch ----------------
extern "C" void kernel_launch(void* const* d_in, const int* in_sizes, int n_in,
                              void* d_out, int out_size, void* d_ws, size_t ws_size,
                              hipStream_t stream) {
    const float* x      = (const float*)d_in[0];
    const float* n1g    = (const float*)d_in[1];
    const float* n1b    = (const float*)d_in[2];
    const float* qkv_w  = (const float*)d_in[3];
    const float* qkv_b  = (const float*)d_in[4];
    const float* rpb    = (const float*)d_in[5];
    const float* proj_w = (const float*)d_in[6];
    const float* proj_b = (const float*)d_in[7];
    const float* n2g    = (const float*)d_in[8];
    const float* n2b    = (const float*)d_in[9];
    const float* fc1_w  = (const float*)d_in[10];
    const float* fc1_b  = (const float*)d_in[11];
    const float* fc2_w  = (const float*)d_in[12];
    const float* fc2_b  = (const float*)d_in[13];
    const float* dw_w   = (const float*)d_in[14];
    const float* dw_b   = (const float*)d_in[15];
    const float* pw_w   = (const float*)d_in[16];
    const float* pw_b   = (const float*)d_in[17];
    const float* bn_g   = (const float*)d_in[18];
    const float* bn_b   = (const float*)d_in[19];
    float* outF = (float*)d_out;

    char* ws = (char*)d_ws;
    float* XF = (float*)ws;
    short* Abuf = (short*)(ws + 50331648);
    short* Bbuf = (short*)(ws + 150994944);
    short* WT = (short*)(ws + 226492416);

    transpose_in<<<dim3(1024, 6, 2), dim3(32, 8), 0, stream>>>(x, XF);
    prep_w<<<7056, 256, 0, stream>>>(qkv_w, proj_w, fc1_w, fc2_w, pw_w, WT);

    for (int i = 0; i < 4; i++) {
        int shifted = i & 1;
        int shift = shifted ? 2 : 0;
        qkv_k<<<512, 256, 0, stream>>>(XF, WT + (long)i * 442368, qkv_b + i * 576,
                                       n1g + i * 192, n1b + i * 192, Bbuf, shift);
        attn_k<<<1536, 256, 0, stream>>>(Bbuf, rpb + i * 2058, Abuf, shifted);
        wk_k<3><<<512, 256, 0, stream>>>(Abuf, WT + (long)i * 442368 + 110592, proj_b + i * 192,
                                         XF, nullptr, nullptr, nullptr, shift);
        mlp_k<<<512, 512, 0, stream>>>(XF, WT + (long)i * 442368 + 147456,
                                       WT + (long)i * 442368 + 294912,
                                       fc1_b + i * 768, fc2_b + i * 192,
                                       n2g + i * 192, n2b + i * 192, XF);
    }

    dw_k<<<8192, 192, 0, stream>>>(XF, dw_w, dw_b, Abuf);
    wk_k<4><<<512, 256, 0, stream>>>(Abuf, WT + 1769472, pw_b,
                                     nullptr, outF, bn_g, bn_b, 0);
}

// Round 16
// 710.640 us; speedup vs baseline: 1.1851x; 1.0720x over previous
//
#include <hip/hip_runtime.h>
#include <hip/hip_bf16.h>

// ---------------- constants ----------------
// C=192, H=W=T=32, WS=4, SS=2, NH=6, HD=32, N=64 tokens/window
// L = 32768 tokens/batch, B=2 -> M = 65536 rows everywhere.
#define DI __device__ __forceinline__

typedef short bf16x8 __attribute__((ext_vector_type(8)));
typedef float f32x4 __attribute__((ext_vector_type(4)));
typedef short s16x4 __attribute__((ext_vector_type(4)));

DI short f2bf(float f) {
    __hip_bfloat16 h = __float2bfloat16(f);
    return *reinterpret_cast<short*>(&h);
}

DI void gload_lds16(const short* gsrc, short* ldst) {
    __builtin_amdgcn_global_load_lds(
        (const __attribute__((address_space(1))) void*)gsrc,
        (__attribute__((address_space(3))) void*)ldst, 16, 0, 0);
}

// region label along one axis for the shift mask: [0,28)->0, [28,30)->1, [30,32)->2
DI int reg3(int p) { return p < 28 ? 0 : (p < 30 ? 1 : 2); }

// ---------------- input transpose: x (B,C,L) -> xf (B,L,C) f32 ----------------
__global__ __launch_bounds__(256) void transpose_in(const float* __restrict__ x,
                                                    float* __restrict__ xf) {
    __shared__ float tile[32][33];
    int b = blockIdx.z;
    int c0 = blockIdx.y * 32;
    int l0 = blockIdx.x * 32;
    int tx = threadIdx.x, ty = threadIdx.y;  // 32 x 8
#pragma unroll
    for (int i = 0; i < 32; i += 8)
        tile[ty + i][tx] = x[(long)(b * 192 + c0 + ty + i) * 32768 + l0 + tx];
    __syncthreads();
#pragma unroll
    for (int i = 0; i < 32; i += 8)
        xf[(long)(b * 32768 + l0 + ty + i) * 192 + c0 + tx] = tile[tx][ty + i];
}

// ---------------- weight prep ----------------
__global__ __launch_bounds__(256) void prep_w(const float* __restrict__ qkv_w,
                                              const float* __restrict__ proj_w,
                                              const float* __restrict__ fc1_w,
                                              const float* __restrict__ fc2_w,
                                              const float* __restrict__ pw_w,
                                              short* __restrict__ wt) {
    int i = blockIdx.x * 256 + threadIdx.x;
    float v;
    if (i < 1769472) {
        int b4 = i / 442368, r = i - b4 * 442368;
        if (r < 110592) { int n = r / 192, k = r - n * 192; v = qkv_w[b4 * 110592 + k * 576 + n]; }
        else if (r < 147456) { int r2 = r - 110592; int n = r2 / 192, k = r2 - n * 192; v = proj_w[b4 * 36864 + k * 192 + n]; }
        else if (r < 294912) { int r2 = r - 147456; int n = r2 / 192, k = r2 - n * 192; v = fc1_w[b4 * 147456 + k * 768 + n]; }
        else { int r2 = r - 294912; int n = r2 / 768, k = r2 - n * 768; v = fc2_w[b4 * 147456 + k * 192 + n]; }
        wt[i] = f2bf(v);
    } else {
        int r = i - 1769472;
        wt[i] = f2bf(pw_w[r]);
    }
}

// ---------------- fused LN1 + QKV: out = LN(gather(x)) @ Wqkv + b ----------------
// Block = 128 rows (window order), 4 waves x 32 rows. A (LN'd) lives in registers.
// W: 9 chunks of 64 cols, double-buffered LDS via async global_load_lds.
__global__ __launch_bounds__(256) void qkv_k(const float* __restrict__ XF,
                                             const short* __restrict__ Wg,  // qkvT (576,192)
                                             const float* __restrict__ bias,
                                             const float* __restrict__ n1g,
                                             const float* __restrict__ n1b,
                                             short* __restrict__ out, int shift) {
    __shared__ short Ws[2][12288];
    const int tid = threadIdx.x;
    const int wv = tid >> 6, lane = tid & 63;
    const int lr = lane & 15, lg = lane >> 4;
    const int mt = ((blockIdx.x & 7) << 6) + (blockIdx.x >> 3);  // XCD swizzle, 512 blocks
    const int m0 = mt << 7;

    // ---- LN1 prologue with roll+window-partition gather ----
    bf16x8 areg[2][6];
#pragma unroll
    for (int mf = 0; mf < 2; mf++) {
        int row = m0 + (wv << 5) + (mf << 4) + lr;
        int b = row >> 15, r = row & 32767, widx = r >> 6, n = r & 63;
        int wh = widx >> 6, ww = (widx >> 3) & 7, wt = widx & 7;
        int ih = n >> 4, iw = (n >> 2) & 3, it = n & 3;
        int h = ((wh << 2) + ih + shift) & 31;
        int w = ((ww << 2) + iw + shift) & 31;
        int t = ((wt << 2) + it + shift) & 31;
        const float* rp = XF + ((long)(b << 15) + (h << 10) + (w << 5) + t) * 192;
        f32x4 xv[6][2];
        float s = 0.f, sq = 0.f;
#pragma unroll
        for (int kk = 0; kk < 6; kk++)
#pragma unroll
            for (int q = 0; q < 2; q++) {
                xv[kk][q] = *(const f32x4*)(rp + kk * 32 + (lg << 3) + q * 4);
#pragma unroll
                for (int e = 0; e < 4; e++) {
                    s += xv[kk][q][e];
                    sq += xv[kk][q][e] * xv[kk][q][e];
                }
            }
        s += __shfl_xor(s, 16, 64); s += __shfl_xor(s, 32, 64);
        sq += __shfl_xor(sq, 16, 64); sq += __shfl_xor(sq, 32, 64);
        float mu = s * (1.f / 192.f);
        float var = sq * (1.f / 192.f) - mu * mu;
        float rstd = rsqrtf(var + 1e-5f);
#pragma unroll
        for (int kk = 0; kk < 6; kk++) {
            int cb = kk * 32 + (lg << 3);
            f32x4 g0 = *(const f32x4*)(n1g + cb), g1 = *(const f32x4*)(n1g + cb + 4);
            f32x4 b0 = *(const f32x4*)(n1b + cb), b1v = *(const f32x4*)(n1b + cb + 4);
            bf16x8 tt;
#pragma unroll
            for (int e = 0; e < 4; e++) {
                tt[e] = f2bf((xv[kk][0][e] - mu) * rstd * g0[e] + b0[e]);
                tt[e + 4] = f2bf((xv[kk][1][e] - mu) * rstd * g1[e] + b1v[e]);
            }
            areg[mf][kk] = tt;
        }
    }

    auto stage = [&](int jc, int buf) {
#pragma unroll
        for (int q = 0; q < 6; q++) {
            int base = (wv * 6 + q) * 512;
            int E = base + lane * 8;
            int row = E / 192;
            int cb = (E - row * 192) >> 3;
            gload_lds16(Wg + (long)(jc * 64 + row) * 192 + ((cb ^ (row & 7)) << 3),
                        &Ws[buf][base]);
        }
    };

    stage(0, 0);
    __syncthreads();

    for (int j = 0; j < 9; j++) {
        if (j < 8) stage(j + 1, (j + 1) & 1);
        const short* W = Ws[j & 1];
        f32x4 acc[2][4] = {};
#pragma unroll
        for (int kk = 0; kk < 6; kk++) {
            int cb = (kk << 2) + lg;
            bf16x8 wf[4];
#pragma unroll
            for (int nf = 0; nf < 4; nf++) {
                int r = (nf << 4) + lr;
                wf[nf] = *(const bf16x8*)(W + r * 192 + ((cb ^ (r & 7)) << 3));
            }
#pragma unroll
            for (int mf = 0; mf < 2; mf++)
#pragma unroll
                for (int nf = 0; nf < 4; nf++)
                    acc[mf][nf] = __builtin_amdgcn_mfma_f32_16x16x32_bf16(
                        areg[mf][kk], wf[nf], acc[mf][nf], 0, 0, 0);
        }
        // store chunk output
#pragma unroll
        for (int mf = 0; mf < 2; mf++) {
#pragma unroll
            for (int nf = 0; nf < 4; nf++) {
                int col = j * 64 + (nf << 4) + lr;
                float bv = bias[col];
#pragma unroll
                for (int e = 0; e < 4; e++) {
                    int row = m0 + (wv << 5) + (mf << 4) + (lg << 2) + e;
                    out[(long)row * 576 + col] = f2bf(acc[mf][nf][e] + bv);
                }
            }
        }
        __syncthreads();
    }
}

// ---------------- A-in-regs GEMM with full W in LDS (K=192, N=192) ----------------
// MODE 3: proj -> window-reverse+roll, resid += v
// MODE 4: pointwise conv -> BN + ReLU, f32 channel-major out
template <int MODE>
__global__ __launch_bounds__(256) void wk_k(const short* __restrict__ A,
                                            const short* __restrict__ Wg,  // (192,192)
                                            const float* __restrict__ bias,
                                            float* __restrict__ resid, float* __restrict__ outF,
                                            const float* __restrict__ bng,
                                            const float* __restrict__ bnb, int shift) {
    __shared__ short Ws[36864];
    const int tid = threadIdx.x;
    const int wv = tid >> 6, lane = tid & 63;
    const int lr = lane & 15, lg = lane >> 4;
    const int mt = ((blockIdx.x & 7) << 6) + (blockIdx.x >> 3);  // 512 blocks
    const int m0 = mt << 7;

    // A rows straight into registers
    bf16x8 areg[2][6];
#pragma unroll
    for (int mf = 0; mf < 2; mf++)
#pragma unroll
        for (int kk = 0; kk < 6; kk++)
            areg[mf][kk] = *(const bf16x8*)(A + (long)(m0 + (wv << 5) + (mf << 4) + lr) * 192 + kk * 32 + (lg << 3));

    // stage full W (async, pre-swizzled source)
#pragma unroll
    for (int q = 0; q < 18; q++) {
        int base = (wv * 18 + q) * 512;
        int E = base + lane * 8;
        int row = E / 192;
        int cb = (E - row * 192) >> 3;
        gload_lds16(Wg + (long)row * 192 + ((cb ^ (row & 7)) << 3), Ws + base);
    }
    __syncthreads();

    f32x4 acc[2][12] = {};
#pragma unroll
    for (int kk = 0; kk < 6; kk++) {
        int cb = (kk << 2) + lg;
#pragma unroll
        for (int njb = 0; njb < 3; njb++) {
            bf16x8 wf[4];
#pragma unroll
            for (int q = 0; q < 4; q++) {
                int r = ((njb * 4 + q) << 4) + lr;
                wf[q] = *(const bf16x8*)(Ws + r * 192 + ((cb ^ (r & 7)) << 3));
            }
#pragma unroll
            for (int mf = 0; mf < 2; mf++)
#pragma unroll
                for (int q = 0; q < 4; q++)
                    acc[mf][njb * 4 + q] = __builtin_amdgcn_mfma_f32_16x16x32_bf16(
                        areg[mf][kk], wf[q], acc[mf][njb * 4 + q], 0, 0, 0);
        }
    }

    // epilogue
#pragma unroll
    for (int mf = 0; mf < 2; mf++) {
        int rbase = m0 + (wv << 5) + (mf << 4) + (lg << 2);
#pragma unroll
        for (int nj = 0; nj < 12; nj++) {
            int col = (nj << 4) + lr;
            float bv = bias[col];
            if (MODE == 4) {
                float sc = 0.9999950000374997f * bng[col];
                float bb = bnb[col];
                f32x4 o;
#pragma unroll
                for (int e = 0; e < 4; e++) {
                    float v = (acc[mf][nj][e] + bv) * sc + bb;
                    o[e] = v > 0.f ? v : 0.f;
                }
                int b = rbase >> 15, l = rbase & 32767;
                *(f32x4*)(outF + ((long)(b * 192 + col) << 15) + l) = o;
            } else {  // MODE 3
#pragma unroll
                for (int e = 0; e < 4; e++) {
                    int r = rbase + e;
                    int b = r >> 15, rr = r & 32767, widx = rr >> 6, n = rr & 63;
                    int wh = widx >> 6, ww = (widx >> 3) & 7, wt = widx & 7;
                    int ih = n >> 4, iw = (n >> 2) & 3, it = n & 3;
                    int h = ((wh << 2) + ih + shift) & 31;
                    int w = ((ww << 2) + iw + shift) & 31;
                    int t = ((wt << 2) + it + shift) & 31;
                    long tok = (long)(b << 15) + (h << 10) + (w << 5) + t;
                    resid[tok * 192 + col] += acc[mf][nj][e] + bv;
                }
            }
        }
    }
}

// ---------------- fused LN2+MLP v5 (proven 73us config) ----------------
__global__ __launch_bounds__(512, 2) void mlp_k(const float* __restrict__ XF,
                                                const short* __restrict__ W1g,  // fc1T (768,192)
                                                const short* __restrict__ W2g,  // fc2T (192,768)
                                                const float* __restrict__ b1,
                                                const float* __restrict__ b2,
                                                const float* __restrict__ n2g,
                                                const float* __restrict__ n2b,
                                                float* __restrict__ resid) {
    __shared__ short Wbuf[2][24576];  // per buf: W1 64x192 @0, W2 192x64 @12288
    __shared__ short Hs[16384];       // 8 waves x 32x64 (XOR-swizzled)
    const int tid = threadIdx.x;
    const int wv = tid >> 6, lane = tid & 63;
    const int lr = lane & 15, lg = lane >> 4;
    const int mt = ((blockIdx.x & 7) << 5) + (blockIdx.x >> 3);  // XCD swizzle, 256 blocks
    const int m0 = mt << 8;
    short* hw = Hs + (wv << 11);  // wave-private 32x64

    bf16x8 areg[2][6];
#pragma unroll
    for (int mf = 0; mf < 2; mf++) {
        const float* rp = XF + (long)(m0 + (wv << 5) + (mf << 4) + lr) * 192;
        f32x4 xv[6][2];
        float s = 0.f, sq = 0.f;
#pragma unroll
        for (int kk = 0; kk < 6; kk++)
#pragma unroll
            for (int q = 0; q < 2; q++) {
                xv[kk][q] = *(const f32x4*)(rp + kk * 32 + (lg << 3) + q * 4);
#pragma unroll
                for (int e = 0; e < 4; e++) {
                    s += xv[kk][q][e];
                    sq += xv[kk][q][e] * xv[kk][q][e];
                }
            }
        s += __shfl_xor(s, 16, 64); s += __shfl_xor(s, 32, 64);
        sq += __shfl_xor(sq, 16, 64); sq += __shfl_xor(sq, 32, 64);
        float mu = s * (1.f / 192.f);
        float var = sq * (1.f / 192.f) - mu * mu;
        float rstd = rsqrtf(var + 1e-5f);
#pragma unroll
        for (int kk = 0; kk < 6; kk++) {
            int cb = kk * 32 + (lg << 3);
            f32x4 g0 = *(const f32x4*)(n2g + cb), g1 = *(const f32x4*)(n2g + cb + 4);
            f32x4 b0 = *(const f32x4*)(n2b + cb), b1v = *(const f32x4*)(n2b + cb + 4);
            bf16x8 t;
#pragma unroll
            for (int e = 0; e < 4; e++) {
                t[e] = f2bf((xv[kk][0][e] - mu) * rstd * g0[e] + b0[e]);
                t[e + 4] = f2bf((xv[kk][1][e] - mu) * rstd * g1[e] + b1v[e]);
            }
            areg[mf][kk] = t;
        }
    }

    auto stage = [&](int jc, int buf) {
#pragma unroll
        for (int q = 0; q < 3; q++) {  // W1 chunk: 64x192
            int base = (wv * 3 + q) * 512;
            int E = base + lane * 8;
            int row = E / 192;
            int cb = (E - row * 192) >> 3;
            gload_lds16(W1g + (long)(jc * 64 + row) * 192 + ((cb ^ (row & 7)) << 3),
                        &Wbuf[buf][base]);
        }
#pragma unroll
        for (int q = 0; q < 3; q++) {  // W2 chunk: 192x64
            int base = (wv * 3 + q) * 512;
            int E = base + lane * 8;
            int row = E >> 6;
            int cb = (E & 63) >> 3;
            gload_lds16(W2g + (long)row * 768 + jc * 64 + ((cb ^ (row & 7)) << 3),
                        &Wbuf[buf][12288 + base]);
        }
    };

    stage(0, 0);
    __syncthreads();

    f32x4 acc[2][12] = {};

    for (int j = 0; j < 12; j++) {
        if (j < 11) stage(j + 1, (j + 1) & 1);
        const short* W1s = Wbuf[j & 1];
        const short* W2s = Wbuf[j & 1] + 12288;

        f32x4 hacc[4][2] = {};
#pragma unroll
        for (int kk = 0; kk < 6; kk++) {
            int cb = (kk << 2) + lg;
            bf16x8 wf[4];
#pragma unroll
            for (int hf = 0; hf < 4; hf++) {
                int r = (hf << 4) + lr;
                wf[hf] = *(const bf16x8*)(W1s + r * 192 + ((cb ^ (r & 7)) << 3));
            }
#pragma unroll
            for (int hf = 0; hf < 4; hf++)
#pragma unroll
                for (int mf = 0; mf < 2; mf++)
                    hacc[hf][mf] = __builtin_amdgcn_mfma_f32_16x16x32_bf16(
                        wf[hf], areg[mf][kk], hacc[hf][mf], 0, 0, 0);
        }

#pragma unroll
        for (int hf = 0; hf < 4; hf++) {
            f32x4 bv = *(const f32x4*)(b1 + j * 64 + (hf << 4) + (lg << 2));
#pragma unroll
            for (int mf = 0; mf < 2; mf++) {
                s16x4 hv;
#pragma unroll
                for (int e = 0; e < 4; e++) {
                    float v = hacc[hf][mf][e] + bv[e];
                    float inner = fmaf(-0.07135481627f, v * v, -1.595769122f);
                    float eterm = __expf(v * inner);  // exp(-2u)
                    float gl = v * __builtin_amdgcn_rcpf(1.f + eterm);
                    hv[e] = f2bf(gl);
                }
                int Mrow = (mf << 4) + lr;
                int blk = (hf << 1) | (lg >> 1);
                *(s16x4*)(hw + Mrow * 64 + ((blk ^ (Mrow & 7)) << 3) + ((lg & 1) << 2)) = hv;
            }
        }
        asm volatile("s_waitcnt lgkmcnt(0)" ::: "memory");

#pragma unroll
        for (int kk = 0; kk < 2; kk++) {
            int cb = (kk << 2) + lg;
            bf16x8 ah[2], bw[12];
#pragma unroll
            for (int mf = 0; mf < 2; mf++) {
                int r = (mf << 4) + lr;
                ah[mf] = *(const bf16x8*)(hw + r * 64 + ((cb ^ (r & 7)) << 3));
            }
#pragma unroll
            for (int nj = 0; nj < 12; nj++) {
                int r = (nj << 4) + lr;
                bw[nj] = *(const bf16x8*)(W2s + r * 64 + ((cb ^ (r & 7)) << 3));
            }
#pragma unroll
            for (int mf = 0; mf < 2; mf++)
#pragma unroll
                for (int nj = 0; nj < 12; nj++)
                    acc[mf][nj] = __builtin_amdgcn_mfma_f32_16x16x32_bf16(
                        ah[mf], bw[nj], acc[mf][nj], 0, 0, 0);
        }
        __syncthreads();
    }

#pragma unroll
    for (int mf = 0; mf < 2; mf++) {
        int rbase = m0 + (wv << 5) + (mf << 4) + (lg << 2);
#pragma unroll
        for (int nj = 0; nj < 12; nj++) {
            int col = (nj << 4) + lr;
            float bv = b2[col];
#pragma unroll
            for (int e = 0; e < 4; e++) {
                long r = rbase + e;
                resid[r * 192 + col] += acc[mf][nj][e] + bv;
            }
        }
    }
}

// ---------------- windowed attention: one wave per (window, head) ----------------
__global__ __launch_bounds__(256) void attn_k(const short* __restrict__ qkv,
                                              const float* __restrict__ rpb,  // (343,6)
                                              short* __restrict__ o, int shifted) {
    __shared__ short lds[4 * 6144];
    const int wv = threadIdx.x >> 6, lane = threadIdx.x & 63;
    short* vT = lds + wv * 6144;
    short* P = lds + wv * 6144 + 2048;
    const int task = blockIdx.x * 4 + wv;
    const int win = task / 6, head = task - win * 6;
    const int lr = lane & 15, lg = lane >> 4;
    const long qbase = (long)win * 64 * 576 + head * 32;

    bf16x8 aq[4], bk[4];
#pragma unroll
    for (int bi = 0; bi < 4; bi++)
        aq[bi] = *(const bf16x8*)(qkv + qbase + (long)((bi << 4) + lr) * 576 + (lg << 3));
#pragma unroll
    for (int bj = 0; bj < 4; bj++)
        bk[bj] = *(const bf16x8*)(qkv + qbase + 192 + (long)((bj << 4) + lr) * 576 + (lg << 3));
    f32x4 s[4][4] = {};
#pragma unroll
    for (int bi = 0; bi < 4; bi++)
#pragma unroll
        for (int bj = 0; bj < 4; bj++)
            s[bi][bj] = __builtin_amdgcn_mfma_f32_16x16x32_bf16(aq[bi], bk[bj], s[bi][bj], 0, 0, 0);

#pragma unroll
    for (int j = 0; j < 4; j++) {
        bf16x8 vv = *(const bf16x8*)(qkv + qbase + 384 + (long)lane * 576 + (j << 3));
#pragma unroll
        for (int e = 0; e < 8; e++) {
            int d = (j << 3) + e;
            vT[d * 64 + (((lane >> 3) ^ (d & 7)) << 3) + (lane & 7)] = vv[e];
        }
    }

    const float SCALE = 0.17677669529663687f;
    int widx = win & 511;
    int wh = widx >> 6, ww = (widx >> 3) & 7, wt = widx & 7;
    int ihm[4], iwm[4], itm[4], lblm[4];
#pragma unroll
    for (int bj = 0; bj < 4; bj++) {
        int m = (bj << 4) + lr;
        ihm[bj] = m >> 4; iwm[bj] = (m >> 2) & 3; itm[bj] = m & 3;
        lblm[bj] = reg3((wh << 2) + ihm[bj]) * 9 + reg3((ww << 2) + iwm[bj]) * 3 + reg3((wt << 2) + itm[bj]);
    }
#pragma unroll
    for (int bi = 0; bi < 4; bi++) {
#pragma unroll
        for (int e = 0; e < 4; e++) {
            int n = (bi << 4) + (lg << 2) + e;
            int ihn = n >> 4, iwn = (n >> 2) & 3, itn = n & 3;
            int lbln = reg3((wh << 2) + ihn) * 9 + reg3((ww << 2) + iwn) * 3 + reg3((wt << 2) + itn);
#pragma unroll
            for (int bj = 0; bj < 4; bj++) {
                int idx = (ihn - ihm[bj] + 3) * 49 + (iwn - iwm[bj] + 3) * 7 + (itn - itm[bj] + 3);
                float bias = rpb[idx * 6 + head];
                float val = s[bi][bj][e] * SCALE + bias;
                if (shifted && lbln != lblm[bj]) val -= 100.f;
                s[bi][bj][e] = val;
            }
        }
    }

#pragma unroll
    for (int bi = 0; bi < 4; bi++) {
#pragma unroll
        for (int e = 0; e < 4; e++) {
            float mx = s[bi][0][e];
#pragma unroll
            for (int bj = 1; bj < 4; bj++) mx = fmaxf(mx, s[bi][bj][e]);
#pragma unroll
            for (int off = 1; off < 16; off <<= 1) mx = fmaxf(mx, __shfl_xor(mx, off, 64));
            float sm = 0.f;
#pragma unroll
            for (int bj = 0; bj < 4; bj++) {
                float p = __expf(s[bi][bj][e] - mx);
                s[bi][bj][e] = p;
                sm += p;
            }
#pragma unroll
            for (int off = 1; off < 16; off <<= 1) sm += __shfl_xor(sm, off, 64);
            float rinv = 1.f / sm;
            int n = (bi << 4) + (lg << 2) + e;
#pragma unroll
            for (int bj = 0; bj < 4; bj++) {
                int m = (bj << 4) + lr;
                P[n * 64 + (((m >> 3) ^ (n & 7)) << 3) + (m & 7)] = f2bf(s[bi][bj][e] * rinv);
            }
        }
    }

    f32x4 oacc[4][2] = {};
#pragma unroll
    for (int ks = 0; ks < 2; ks++) {
        bf16x8 ap[4], bv2[2];
        int kb = (ks << 2) + lg;
#pragma unroll
        for (int bi = 0; bi < 4; bi++) {
            int r = (bi << 4) + lr;
            ap[bi] = *(const bf16x8*)(P + r * 64 + ((kb ^ (r & 7)) << 3));
        }
#pragma unroll
        for (int nf = 0; nf < 2; nf++) {
            int d = (nf << 4) + lr;
            bv2[nf] = *(const bf16x8*)(vT + d * 64 + ((kb ^ (d & 7)) << 3));
        }
#pragma unroll
        for (int bi = 0; bi < 4; bi++)
#pragma unroll
            for (int nf = 0; nf < 2; nf++)
                oacc[bi][nf] = __builtin_amdgcn_mfma_f32_16x16x32_bf16(ap[bi], bv2[nf], oacc[bi][nf], 0, 0, 0);
    }
#pragma unroll
    for (int bi = 0; bi < 4; bi++)
#pragma unroll
        for (int nf = 0; nf < 2; nf++)
#pragma unroll
            for (int e = 0; e < 4; e++) {
                int n = (bi << 4) + (lg << 2) + e;
                int d = (nf << 4) + lr;
                o[((long)win * 64 + n) * 192 + head * 32 + d] = f2bf(oacc[bi][nf][e]);
            }
}

// ---------------- depthwise 3x3x3 conv, register-blocked along t ----------------
__global__ __launch_bounds__(192) void dw_k(const float* __restrict__ xf,
                                            const float* __restrict__ w,
                                            const float* __restrict__ db,
                                            short* __restrict__ out) {
    int c = threadIdx.x;
    int blk = blockIdx.x;
    int t0 = (blk & 3) << 3;
    int bhw = blk >> 2;
    int b = bhw >> 10, h = (bhw >> 5) & 31, wq = bhw & 31;

    float wr[27];
#pragma unroll
    for (int k = 0; k < 27; k++) wr[k] = w[c * 27 + k];
    float bias = db[c];
    float acc[8];
#pragma unroll
    for (int j = 0; j < 8; j++) acc[j] = bias;

#pragma unroll
    for (int a = 0; a < 3; a++) {
        int hh = h + a - 1;
        if (hh < 0 || hh > 31) continue;
#pragma unroll
        for (int bb = 0; bb < 3; bb++) {
            int ww = wq + bb - 1;
            if (ww < 0 || ww > 31) continue;
            const float* base = xf + ((long)(b << 15) + (hh << 10) + (ww << 5)) * 192 + c;
            float val[10];
#pragma unroll
            for (int tt = 0; tt < 10; tt++) {
                int t = t0 + tt - 1;
                val[tt] = (t >= 0 && t < 32) ? base[t * 192] : 0.f;
            }
#pragma unroll
            for (int d = 0; d < 3; d++) {
                float wv = wr[a * 9 + bb * 3 + d];
#pragma unroll
                for (int j = 0; j < 8; j++)
                    acc[j] = fmaf(val[j + d], wv, acc[j]);
            }
        }
    }
    long obase = ((long)(b << 15) + (h << 10) + (wq << 5) + t0) * 192 + c;
#pragma unroll
    for (int j = 0; j < 8; j++) out[obase + j * 192] = f2bf(acc[j]);
}

// ---------------- launch ----------------
extern "C" void kernel_launch(void* const* d_in, const int* in_sizes, int n_in,
                              void* d_out, int out_size, void* d_ws, size_t ws_size,
                              hipStream_t stream) {
    const float* x      = (const float*)d_in[0];
    const float* n1g    = (const float*)d_in[1];
    const float* n1b    = (const float*)d_in[2];
    const float* qkv_w  = (const float*)d_in[3];
    const float* qkv_b  = (const float*)d_in[4];
    const float* rpb    = (const float*)d_in[5];
    const float* proj_w = (const float*)d_in[6];
    const float* proj_b = (const float*)d_in[7];
    const float* n2g    = (const float*)d_in[8];
    const float* n2b    = (const float*)d_in[9];
    const float* fc1_w  = (const float*)d_in[10];
    const float* fc1_b  = (const float*)d_in[11];
    const float* fc2_w  = (const float*)d_in[12];
    const float* fc2_b  = (const float*)d_in[13];
    const float* dw_w   = (const float*)d_in[14];
    const float* dw_b   = (const float*)d_in[15];
    const float* pw_w   = (const float*)d_in[16];
    const float* pw_b   = (const float*)d_in[17];
    const float* bn_g   = (const float*)d_in[18];
    const float* bn_b   = (const float*)d_in[19];
    float* outF = (float*)d_out;

    char* ws = (char*)d_ws;
    float* XF = (float*)ws;
    short* Abuf = (short*)(ws + 50331648);
    short* Bbuf = (short*)(ws + 150994944);
    short* WT = (short*)(ws + 226492416);

    transpose_in<<<dim3(1024, 6, 2), dim3(32, 8), 0, stream>>>(x, XF);
    prep_w<<<7056, 256, 0, stream>>>(qkv_w, proj_w, fc1_w, fc2_w, pw_w, WT);

    for (int i = 0; i < 4; i++) {
        int shifted = i & 1;
        int shift = shifted ? 2 : 0;
        qkv_k<<<512, 256, 0, stream>>>(XF, WT + (long)i * 442368, qkv_b + i * 576,
                                       n1g + i * 192, n1b + i * 192, Bbuf, shift);
        attn_k<<<1536, 256, 0, stream>>>(Bbuf, rpb + i * 2058, Abuf, shifted);
        wk_k<3><<<512, 256, 0, stream>>>(Abuf, WT + (long)i * 442368 + 110592, proj_b + i * 192,
                                         XF, nullptr, nullptr, nullptr, shift);
        mlp_k<<<256, 512, 0, stream>>>(XF, WT + (long)i * 442368 + 147456,
                                       WT + (long)i * 442368 + 294912,
                                       fc1_b + i * 768, fc2_b + i * 192,
                                       n2g + i * 192, n2b + i * 192, XF);
    }

    dw_k<<<8192, 192, 0, stream>>>(XF, dw_w, dw_b, Abuf);
    wk_k<4><<<512, 256, 0, stream>>>(Abuf, WT + 1769472, pw_b,
                                     nullptr, outF, bn_g, bn_b, 0);
}